// Round 3
// baseline (1090.600 us; speedup 1.0000x reference)
//
#include <hip/hip_runtime.h>

// ---------------------------------------------------------------------------
// ACBlock: BN1+ReLU -> Performer attention -> +x -> BN2+ReLU -> conv3x3 -> +x
// B=16 C=256 H=W=56  S=3136 tokens/batch, NTOK=50176, heads=8, d=32, m=110
// All matmuls in bf16 MFMA 16x16x32. BN applied on the fly in GEMM staging.
// WS budget 54.2 MB: q lives in d_out (conv fully overwrites it later);
// Yt aliases dead k; bf16 z aliases dead v. Runtime ws_size guard -> clean
// numeric failure instead of OOB container kill.
// ---------------------------------------------------------------------------

typedef short short8 __attribute__((ext_vector_type(8)));
typedef float f32x4 __attribute__((ext_vector_type(4)));

#define DEVI static __device__ __forceinline__

#define CDIM 256
#define SDIM 3136
#define NTOK 50176
#define NHEAD 8
#define DHEAD 32
#define MFEAT 110
#define NORMC 0.42044820762685725f  // 32^-0.25
#define NPIX 50176.0f

DEVI unsigned short f2bf(float f) {
  union { float f; unsigned u; } v; v.f = f;
  unsigned r = v.u + 0x7fffu + ((v.u >> 16) & 1u);
  return (unsigned short)(r >> 16);
}

DEVI float bf2f(short h) {
  union { unsigned u; float f; } v;
  v.u = ((unsigned)(unsigned short)h) << 16;
  return v.f;
}

DEVI f32x4 mfma16(short8 a, short8 b, f32x4 c) {
  return __builtin_amdgcn_mfma_f32_16x16x32_bf16(a, b, c, 0, 0, 0);
}

DEVI unsigned long long pack4(const unsigned short* h) {
  return (unsigned long long)(h[0] | ((unsigned)h[1] << 16)) |
         ((unsigned long long)(h[2] | ((unsigned)h[3] << 16)) << 32);
}

// ---------------------------------------------------------------------------
__global__ void zero_kernel(float* p, int n) {
  for (int i = blockIdx.x * blockDim.x + threadIdx.x; i < n; i += gridDim.x * blockDim.x)
    p[i] = 0.f;
}

// Build bf16 B-operands: Bqkv[768][256] (= [sel*256+cout][cin]), WoT[256][256],
// Bconv[256][2304] (= [oc][off*256+cin]), projb[128][32] (norm folded, rows>=110 zero)
__global__ void prep_kernel(const float* __restrict__ Wq, const float* __restrict__ Wk,
                            const float* __restrict__ Wv, const float* __restrict__ Wo,
                            const float* __restrict__ proj, const float* __restrict__ conv_w,
                            short* __restrict__ Bqkv, short* __restrict__ WoT,
                            short* __restrict__ Bconv, short* __restrict__ projb) {
  const int t0 = blockIdx.x * blockDim.x + threadIdx.x;
  const int stride = gridDim.x * blockDim.x;
  for (int idx = t0; idx < 768 * 256; idx += stride) {
    const int n = idx >> 8, k = idx & 255;
    const float* W = (n < 256) ? Wq : ((n < 512) ? Wk : Wv);
    Bqkv[idx] = (short)f2bf(W[k * 256 + (n & 255)]);
  }
  for (int idx = t0; idx < 256 * 256; idx += stride) {
    const int oc = idx >> 8, k = idx & 255;
    WoT[idx] = (short)f2bf(Wo[k * 256 + oc]);
  }
  for (int idx = t0; idx < 256 * 2304; idx += stride) {
    const int oc = idx / 2304, r = idx - oc * 2304;
    const int off = r >> 8, c = r & 255;
    Bconv[idx] = (short)f2bf(conv_w[(oc * 256 + c) * 9 + off]);
  }
  for (int idx = t0; idx < 128 * 32; idx += stride) {
    const int row = idx >> 5, kk = idx & 31;
    const float v = (row < MFEAT) ? proj[row * 32 + kk] * NORMC : 0.f;
    projb[idx] = (short)f2bf(v);
  }
}

// per-channel sum / sumsq over (B,H,W); grid = B*C blocks (fp32 source)
__global__ void bn_stats_kernel(const float* __restrict__ src, float* __restrict__ sums) {
  const int c = blockIdx.x & 255, b = blockIdx.x >> 8;
  const float* p = src + ((size_t)b * CDIM + c) * SDIM;
  float s = 0.f, s2 = 0.f;
  for (int i = threadIdx.x; i < SDIM; i += 256) {
    const float v = p[i];
    s += v; s2 += v * v;
  }
  for (int o = 32; o > 0; o >>= 1) { s += __shfl_down(s, o); s2 += __shfl_down(s2, o); }
  __shared__ float ls[4], ls2[4];
  const int w = threadIdx.x >> 6;
  if ((threadIdx.x & 63) == 0) { ls[w] = s; ls2[w] = s2; }
  __syncthreads();
  if (threadIdx.x == 0) {
    s = ls[0] + ls[1] + ls[2] + ls[3];
    s2 = ls2[0] + ls2[1] + ls2[2] + ls2[3];
    atomicAdd(&sums[c], s);
    atomicAdd(&sums[256 + c], s2);
  }
}

// bf16-source variant (for z)
__global__ void bn_stats_bf16_kernel(const short* __restrict__ src, float* __restrict__ sums) {
  const int c = blockIdx.x & 255, b = blockIdx.x >> 8;
  const short* p = src + ((size_t)b * CDIM + c) * SDIM;
  float s = 0.f, s2 = 0.f;
  for (int i = threadIdx.x; i < SDIM; i += 256) {
    const float v = bf2f(p[i]);
    s += v; s2 += v * v;
  }
  for (int o = 32; o > 0; o >>= 1) { s += __shfl_down(s, o); s2 += __shfl_down(s2, o); }
  __shared__ float ls[4], ls2[4];
  const int w = threadIdx.x >> 6;
  if ((threadIdx.x & 63) == 0) { ls[w] = s; ls2[w] = s2; }
  __syncthreads();
  if (threadIdx.x == 0) {
    s = ls[0] + ls[1] + ls[2] + ls[3];
    s2 = ls2[0] + ls2[1] + ls2[2] + ls2[3];
    atomicAdd(&sums[c], s);
    atomicAdd(&sums[256 + c], s2);
  }
}

__global__ void bn_final_kernel(const float* __restrict__ sums, const float* __restrict__ gamma,
                                const float* __restrict__ beta, float* __restrict__ scsh) {
  const int c = threadIdx.x;
  const float mean = sums[c] * (1.f / NPIX);
  const float var = sums[256 + c] * (1.f / NPIX) - mean * mean;
  const float sc = gamma[c] * rsqrtf(var + 1e-5f);
  scsh[c] = sc;
  scsh[256 + c] = beta[c] - mean * sc;
}

// ---------------------------------------------------------------------------
// QKV GEMM: A[token][cin] = relu(bn1(x)) staged on the fly, B = Bqkv[col][cin].
// Writes q,k as [b][h][s][d] bf16; v transposed as [b][h][d][s] bf16.
__global__ __launch_bounds__(256, 2)
void qkv_gemm(const float* __restrict__ x, const float* __restrict__ scsh,
              const short* __restrict__ BT, const float* __restrict__ bq,
              const float* __restrict__ bk, const float* __restrict__ bv,
              short* __restrict__ qo, short* __restrict__ ko, short* __restrict__ vo) {
  __shared__ short A_s[128 * 256];  // [tok][cin], 16B-chunk xor swizzle
  const int tid = threadIdx.x;
  const int mtile = blockIdx.x, ntile = blockIdx.y;
  const int tokl = tid & 127, half = tid >> 7;
  const int token = mtile * 128 + tokl;
  const int b = token / SDIM, s = token - b * SDIM;
  const float* xb = x + (size_t)b * CDIM * SDIM + s;
#pragma unroll 4
  for (int g = 0; g < 32; ++g) {
    const int c0 = half * 128 + g * 4;
    unsigned short h4[4];
#pragma unroll
    for (int j = 0; j < 4; ++j) {
      const int c = c0 + j;
      float val = xb[(size_t)c * SDIM];
      val = fmaxf(val * scsh[c] + scsh[256 + c], 0.f);
      h4[j] = f2bf(val);
    }
    const int phys = (c0 >> 3) ^ (tokl & 31);
    *(unsigned long long*)&A_s[tokl * 256 + phys * 8 + (c0 & 4)] = pack4(h4);
  }
  __syncthreads();

  const int lane = tid & 63, wv = tid >> 6;
  const int wm = wv & 1, wn = wv >> 1;
  const int quad = lane >> 4, l15 = lane & 15;
  const f32x4 vzero = {0.f, 0.f, 0.f, 0.f};
  f32x4 acc[4][4];
#pragma unroll
  for (int i = 0; i < 4; ++i)
#pragma unroll
    for (int j = 0; j < 4; ++j) acc[i][j] = vzero;
  const short* Bb = BT + (size_t)(ntile * 128 + wn * 64 + l15) * 256;
#pragma unroll
  for (int ks = 0; ks < 8; ++ks) {
    short8 af[4], bfr[4];
#pragma unroll
    for (int rf = 0; rf < 4; ++rf) {
      const int row = wm * 64 + rf * 16 + l15;
      const int phys = (ks * 4 + quad) ^ (row & 31);
      af[rf] = *(const short8*)&A_s[row * 256 + phys * 8];
    }
#pragma unroll
    for (int cf = 0; cf < 4; ++cf)
      bfr[cf] = *(const short8*)&Bb[cf * 16 * 256 + ks * 32 + quad * 8];
#pragma unroll
    for (int rf = 0; rf < 4; ++rf)
#pragma unroll
      for (int cf = 0; cf < 4; ++cf)
        acc[rf][cf] = mfma16(af[rf], bfr[cf], acc[rf][cf]);
  }

  const int sel = ntile >> 1;  // 0=q 1=k 2=v (uniform per block)
#pragma unroll
  for (int cf = 0; cf < 4; ++cf) {
    const int col = ntile * 128 + wn * 64 + cf * 16 + l15;
    const int chn = col & 255, head = chn >> 5, dd = chn & 31;
    const float bias = (sel == 0) ? bq[chn] : ((sel == 1) ? bk[chn] : bv[chn]);
#pragma unroll
    for (int rf = 0; rf < 4; ++rf) {
      const int tokb = mtile * 128 + wm * 64 + rf * 16 + quad * 4;
      const int bb = tokb / SDIM, ss = tokb - bb * SDIM;  // 4-token group never crosses b
      if (sel < 2) {
        short* dst = (sel == 0) ? qo : ko;
        short* p = dst + ((size_t)(bb * NHEAD + head) * SDIM) * DHEAD + dd;
#pragma unroll
        for (int r = 0; r < 4; ++r)
          p[(size_t)(ss + r) * DHEAD] = (short)f2bf(acc[rf][cf][r] + bias);
      } else {
        unsigned short h4[4];
#pragma unroll
        for (int r = 0; r < 4; ++r) h4[r] = f2bf(acc[rf][cf][r] + bias);
        *(unsigned long long*)(vo + ((size_t)(bb * NHEAD + head) * DHEAD + dd) * SDIM + ss) = pack4(h4);
      }
    }
  }
}

// ---------------------------------------------------------------------------
// Phase 1: per (b,h): phi_k = relu(k @ projb^T)+eps via MFMA (K=32),
// LDS round-trip [mf][tok], then ctx[mf][d] += phi_k^T @ v, ksum[mf] += sums.
__global__ __launch_bounds__(256, 2)
void attn_phase1(const short* __restrict__ kk, const short* __restrict__ vt,
                 const short* __restrict__ projb, float* __restrict__ ctx_acc,
                 float* __restrict__ ksum) {
  __shared__ short proj_s[128 * 40];
  __shared__ short phi_s[4][128 * 40];  // per-wave private [mf][tok] pitch 40
  const int tid = threadIdx.x;
  const int bh = blockIdx.x >> 1, halfI = blockIdx.x & 1;
  for (int i = tid; i < 128 * 32; i += 256)
    proj_s[(i >> 5) * 40 + (i & 31)] = projb[i];
  __syncthreads();
  const int lane = tid & 63, wv = tid >> 6;
  const int quad = lane >> 4, l15 = lane & 15;
  const short* kb = kk + (size_t)bh * SDIM * DHEAD;
  const short* vb = vt + (size_t)bh * DHEAD * SDIM;
  short* myphi = phi_s[wv];
  const f32x4 vzero = {0.f, 0.f, 0.f, 0.f};
  f32x4 cacc[8][2];
  float ks_acc[8];
#pragma unroll
  for (int i = 0; i < 8; ++i) { cacc[i][0] = vzero; cacc[i][1] = vzero; ks_acc[i] = 0.f; }

  for (int ch = halfI * 4 + wv; ch < 98; ch += 8) {
    const int tok0 = ch * 32;
    short8 afr[2];
    afr[0] = *(const short8*)&kb[(size_t)(tok0 + l15) * DHEAD + quad * 8];
    afr[1] = *(const short8*)&kb[(size_t)(tok0 + 16 + l15) * DHEAD + quad * 8];
#pragma unroll
    for (int cf = 0; cf < 8; ++cf) {
      const short8 bfr = *(const short8*)&proj_s[(cf * 16 + l15) * 40 + quad * 8];
      const float epsv = (cf < 6) ? 1e-3f : ((cf == 6) ? ((l15 < 14) ? 1e-3f : 0.f) : 0.f);
#pragma unroll
      for (int fr = 0; fr < 2; ++fr) {
        f32x4 p = mfma16(afr[fr], bfr, vzero);
        unsigned short h4[4];
        float srow = 0.f;
#pragma unroll
        for (int r = 0; r < 4; ++r) {
          const float pv = fmaxf(p[r], 0.f) + epsv;
          srow += pv;
          h4[r] = f2bf(pv);
        }
        ks_acc[cf] += srow;
        *(unsigned long long*)&myphi[(cf * 16 + l15) * 40 + fr * 16 + quad * 4] = pack4(h4);
      }
    }
    short8 bv2[2];
    bv2[0] = *(const short8*)&vb[(size_t)l15 * SDIM + tok0 + quad * 8];
    bv2[1] = *(const short8*)&vb[(size_t)(16 + l15) * SDIM + tok0 + quad * 8];
#pragma unroll
    for (int mfr = 0; mfr < 8; ++mfr) {
      const short8 a2 = *(const short8*)&myphi[(mfr * 16 + l15) * 40 + quad * 8];
      cacc[mfr][0] = mfma16(a2, bv2[0], cacc[mfr][0]);
      cacc[mfr][1] = mfma16(a2, bv2[1], cacc[mfr][1]);
    }
  }
#pragma unroll
  for (int cf = 0; cf < 8; ++cf) {
    float v = ks_acc[cf];
    v += __shfl_xor(v, 16);
    v += __shfl_xor(v, 32);
    if (lane < 16) atomicAdd(&ksum[bh * 128 + cf * 16 + lane], v);
  }
  float* cb = ctx_acc + (size_t)bh * 4096;
#pragma unroll
  for (int mfr = 0; mfr < 8; ++mfr)
#pragma unroll
    for (int df = 0; df < 2; ++df)
#pragma unroll
      for (int r = 0; r < 4; ++r)
        atomicAdd(&cb[(mfr * 16 + quad * 4 + r) * 32 + df * 16 + l15], cacc[mfr][df][r]);
}

// ctx_T[bh][48][128] bf16: rows 0..31 = ctx^T (d-major), row 32 = ksum, 33..47 = 0
__global__ void ctx_finalize(const float* __restrict__ ctx_acc, const float* __restrict__ ksum,
                             short* __restrict__ ctx_T) {
  const int bh = blockIdx.x;
  const float* ca = ctx_acc + (size_t)bh * 4096;
  const float* ks = ksum + bh * 128;
  short* ct = ctx_T + (size_t)bh * 48 * 128;
  for (int i = threadIdx.x; i < 48 * 128; i += 256) {
    const int row = i >> 7, mf = i & 127;
    const float v = (row < 32) ? ca[mf * 32 + row] : ((row == 32) ? ks[mf] : 0.f);
    ct[i] = (short)f2bf(v);
  }
}

// Phase 2: phi_q via MFMA, LDS [tok][mf], out[tok][0..31] = phi_q@ctx, col32 = denom.
// Writes Y_t[b][c=h*32+d][s] bf16.
__global__ __launch_bounds__(256, 2)
void attn_phase2(const short* __restrict__ qq, const short* __restrict__ ctx_T,
                 const short* __restrict__ projb, short* __restrict__ Yt) {
  __shared__ short proj_s[128 * 40];
  __shared__ short ctx_s[48 * 136];
  __shared__ short phi_s[4][32 * 136];  // per-wave [tok][mf] pitch 136
  const int tid = threadIdx.x;
  const int bh = blockIdx.x >> 1, halfI = blockIdx.x & 1;
  for (int i = tid; i < 128 * 32; i += 256)
    proj_s[(i >> 5) * 40 + (i & 31)] = projb[i];
  {
    const short* ct = ctx_T + (size_t)bh * 48 * 128;
    for (int i = tid; i < 48 * 128; i += 256)
      ctx_s[(i >> 7) * 136 + (i & 127)] = ct[i];
  }
  __syncthreads();
  const int lane = tid & 63, wv = tid >> 6;
  const int quad = lane >> 4, l15 = lane & 15;
  const int b = bh >> 3, head = bh & 7;
  const short* qb = qq + (size_t)bh * SDIM * DHEAD;
  short* yb = Yt + ((size_t)b * CDIM + head * DHEAD) * SDIM;
  short* myphi = phi_s[wv];
  const f32x4 vzero = {0.f, 0.f, 0.f, 0.f};

  for (int ch = halfI * 4 + wv; ch < 98; ch += 8) {
    const int tok0 = ch * 32;
    short8 afr[2];
    afr[0] = *(const short8*)&qb[(size_t)(tok0 + l15) * DHEAD + quad * 8];
    afr[1] = *(const short8*)&qb[(size_t)(tok0 + 16 + l15) * DHEAD + quad * 8];
#pragma unroll
    for (int cf = 0; cf < 8; ++cf) {
      const short8 bfr = *(const short8*)&proj_s[(cf * 16 + l15) * 40 + quad * 8];
      const float epsv = (cf < 6) ? 1e-3f : ((cf == 6) ? ((l15 < 14) ? 1e-3f : 0.f) : 0.f);
#pragma unroll
      for (int fr = 0; fr < 2; ++fr) {
        f32x4 p = mfma16(afr[fr], bfr, vzero);
#pragma unroll
        for (int r = 0; r < 4; ++r) {
          const float pv = fmaxf(p[r], 0.f) + epsv;
          myphi[(fr * 16 + quad * 4 + r) * 136 + cf * 16 + l15] = (short)f2bf(pv);
        }
      }
    }
    f32x4 oacc[2][3];
#pragma unroll
    for (int fr = 0; fr < 2; ++fr)
#pragma unroll
      for (int c3 = 0; c3 < 3; ++c3) oacc[fr][c3] = vzero;
#pragma unroll
    for (int ksI = 0; ksI < 4; ++ksI) {
      short8 a3[2];
      a3[0] = *(const short8*)&myphi[l15 * 136 + ksI * 32 + quad * 8];
      a3[1] = *(const short8*)&myphi[(16 + l15) * 136 + ksI * 32 + quad * 8];
#pragma unroll
      for (int c3 = 0; c3 < 3; ++c3) {
        const short8 b3 = *(const short8*)&ctx_s[(c3 * 16 + l15) * 136 + ksI * 32 + quad * 8];
        oacc[0][c3] = mfma16(a3[0], b3, oacc[0][c3]);
        oacc[1][c3] = mfma16(a3[1], b3, oacc[1][c3]);
      }
    }
#pragma unroll
    for (int fr = 0; fr < 2; ++fr) {
      float dinv[4];
#pragma unroll
      for (int r = 0; r < 4; ++r) {
        const float den = __shfl(oacc[fr][2][r], quad << 4);
        dinv[r] = 1.f / den;
      }
#pragma unroll
      for (int c3 = 0; c3 < 2; ++c3) {
        const int d = c3 * 16 + l15;
        unsigned short h4[4];
#pragma unroll
        for (int r = 0; r < 4; ++r) h4[r] = f2bf(oacc[fr][c3][r] * dinv[r]);
        const int ss = tok0 + fr * 16 + quad * 4;
        *(unsigned long long*)&yb[(size_t)d * SDIM + ss] = pack4(h4);
      }
    }
  }
}

// ---------------------------------------------------------------------------
// Wo GEMM: z = Y @ Wo + bo + x  (z bf16 NCHW)
__global__ __launch_bounds__(256, 2)
void wo_gemm(const short* __restrict__ Yt, const short* __restrict__ WoT,
             const float* __restrict__ bo, const float* __restrict__ x,
             short* __restrict__ z) {
  __shared__ short A_s[128 * 256];
  const int tid = threadIdx.x;
  const int mtile = blockIdx.x, ntile = blockIdx.y;
  const int tokl = tid & 127, half = tid >> 7;
  const int token = mtile * 128 + tokl;
  const int b = token / SDIM, s = token - b * SDIM;
  const short* yb = Yt + (size_t)b * CDIM * SDIM + s;
#pragma unroll 4
  for (int g = 0; g < 32; ++g) {
    const int c0 = half * 128 + g * 4;
    unsigned short h4[4];
#pragma unroll
    for (int j = 0; j < 4; ++j)
      h4[j] = (unsigned short)yb[(size_t)(c0 + j) * SDIM];
    const int phys = (c0 >> 3) ^ (tokl & 31);
    *(unsigned long long*)&A_s[tokl * 256 + phys * 8 + (c0 & 4)] = pack4(h4);
  }
  __syncthreads();

  const int lane = tid & 63, wv = tid >> 6;
  const int wm = wv & 1, wn = wv >> 1;
  const int quad = lane >> 4, l15 = lane & 15;
  const f32x4 vzero = {0.f, 0.f, 0.f, 0.f};
  f32x4 acc[4][4];
#pragma unroll
  for (int i = 0; i < 4; ++i)
#pragma unroll
    for (int j = 0; j < 4; ++j) acc[i][j] = vzero;
  const short* Bb = WoT + (size_t)(ntile * 128 + wn * 64 + l15) * 256;
#pragma unroll
  for (int ks = 0; ks < 8; ++ks) {
    short8 af[4], bfr[4];
#pragma unroll
    for (int rf = 0; rf < 4; ++rf) {
      const int row = wm * 64 + rf * 16 + l15;
      const int phys = (ks * 4 + quad) ^ (row & 31);
      af[rf] = *(const short8*)&A_s[row * 256 + phys * 8];
    }
#pragma unroll
    for (int cf = 0; cf < 4; ++cf)
      bfr[cf] = *(const short8*)&Bb[cf * 16 * 256 + ks * 32 + quad * 8];
#pragma unroll
    for (int rf = 0; rf < 4; ++rf)
#pragma unroll
      for (int cf = 0; cf < 4; ++cf)
        acc[rf][cf] = mfma16(af[rf], bfr[cf], acc[rf][cf]);
  }
#pragma unroll
  for (int cf = 0; cf < 4; ++cf) {
    const int oc = ntile * 128 + wn * 64 + cf * 16 + l15;
    const float bias = bo[oc];
#pragma unroll
    for (int rf = 0; rf < 4; ++rf) {
      const int tokb = mtile * 128 + wm * 64 + rf * 16 + quad * 4;
      const int bb = tokb / SDIM, ss = tokb - bb * SDIM;
      const size_t base = ((size_t)(bb * CDIM + oc)) * SDIM + ss;
      const f32x4 xv = *(const f32x4*)(x + base);
      unsigned short h4[4];
#pragma unroll
      for (int r = 0; r < 4; ++r) h4[r] = f2bf(acc[rf][cf][r] + bias + xv[r]);
      *(unsigned long long*)(z + base) = pack4(h4);
    }
  }
}

// ---------------------------------------------------------------------------
// Conv 3x3 implicit GEMM: A[pos][off*256+c] = relu(bn2(z)) patch (0 outside),
// B = Bconv[oc][off*256+c]. Epilogue adds residual x. K-loop = 9 offsets.
__global__ __launch_bounds__(256, 2)
void conv_gemm(const short* __restrict__ z, const float* __restrict__ scsh,
               const short* __restrict__ Bc, const float* __restrict__ x,
               float* __restrict__ out) {
  __shared__ short A_s[128 * 256];
  const int tid = threadIdx.x;
  const int mtile = blockIdx.x, ntile = blockIdx.y;
  const int tokl = tid & 127, half = tid >> 7;
  const int token = mtile * 128 + tokl;
  const int b = token / SDIM, s = token - b * SDIM;
  const int yy = s / 56, xx = s - yy * 56;
  const short* zb = z + (size_t)b * CDIM * SDIM;
  const int lane = tid & 63, wv = tid >> 6;
  const int wm = wv & 1, wn = wv >> 1;
  const int quad = lane >> 4, l15 = lane & 15;
  const f32x4 vzero = {0.f, 0.f, 0.f, 0.f};
  f32x4 acc[4][4];
#pragma unroll
  for (int i = 0; i < 4; ++i)
#pragma unroll
    for (int j = 0; j < 4; ++j) acc[i][j] = vzero;

  for (int off = 0; off < 9; ++off) {
    const int dy = off / 3 - 1, dx = off - (off / 3) * 3 - 1;
    const int ny = yy + dy, nx = xx + dx;
    const bool valid = ((unsigned)ny < 56u) && ((unsigned)nx < 56u);
    const long soff = (long)ny * 56 + nx;
    __syncthreads();
#pragma unroll 4
    for (int g = 0; g < 32; ++g) {
      const int c0 = half * 128 + g * 4;
      unsigned short h4[4];
#pragma unroll
      for (int j = 0; j < 4; ++j) {
        const int c = c0 + j;
        float uval = 0.f;
        if (valid) {
          const float val = bf2f(zb[(long)c * SDIM + soff]);
          uval = fmaxf(val * scsh[c] + scsh[256 + c], 0.f);
        }
        h4[j] = f2bf(uval);
      }
      const int phys = (c0 >> 3) ^ (tokl & 31);
      *(unsigned long long*)&A_s[tokl * 256 + phys * 8 + (c0 & 4)] = pack4(h4);
    }
    __syncthreads();
    const short* Bb = Bc + (size_t)(ntile * 128 + wn * 64 + l15) * 2304 + off * 256;
#pragma unroll
    for (int ks = 0; ks < 8; ++ks) {
      short8 af[4], bfr[4];
#pragma unroll
      for (int rf = 0; rf < 4; ++rf) {
        const int row = wm * 64 + rf * 16 + l15;
        const int phys = (ks * 4 + quad) ^ (row & 31);
        af[rf] = *(const short8*)&A_s[row * 256 + phys * 8];
      }
#pragma unroll
      for (int cf = 0; cf < 4; ++cf)
        bfr[cf] = *(const short8*)&Bb[(size_t)cf * 16 * 2304 + ks * 32 + quad * 8];
#pragma unroll
      for (int rf = 0; rf < 4; ++rf)
#pragma unroll
        for (int cf = 0; cf < 4; ++cf)
          acc[rf][cf] = mfma16(af[rf], bfr[cf], acc[rf][cf]);
    }
  }
#pragma unroll
  for (int cf = 0; cf < 4; ++cf) {
    const int oc = ntile * 128 + wn * 64 + cf * 16 + l15;
#pragma unroll
    for (int rf = 0; rf < 4; ++rf) {
      const int tokb = mtile * 128 + wm * 64 + rf * 16 + quad * 4;
      const int bb = tokb / SDIM, ss = tokb - bb * SDIM;
      const size_t base = ((size_t)(bb * CDIM + oc)) * SDIM + ss;
      const f32x4 xv = *(const f32x4*)(x + base);
      f32x4 res;
#pragma unroll
      for (int r = 0; r < 4; ++r) res[r] = acc[rf][cf][r] + xv[r];
      *(f32x4*)(out + base) = res;
    }
  }
}

// ---------------------------------------------------------------------------
extern "C" void kernel_launch(void* const* d_in, const int* in_sizes, int n_in,
                              void* d_out, int out_size, void* d_ws, size_t ws_size,
                              hipStream_t stream) {
  const float* x      = (const float*)d_in[0];
  const float* bn1_g  = (const float*)d_in[1];
  const float* bn1_b  = (const float*)d_in[2];
  const float* bn2_g  = (const float*)d_in[3];
  const float* bn2_b  = (const float*)d_in[4];
  const float* Wq     = (const float*)d_in[5];
  const float* bq     = (const float*)d_in[6];
  const float* Wk     = (const float*)d_in[7];
  const float* bk     = (const float*)d_in[8];
  const float* Wv     = (const float*)d_in[9];
  const float* bv     = (const float*)d_in[10];
  const float* Wo     = (const float*)d_in[11];
  const float* bo     = (const float*)d_in[12];
  const float* proj   = (const float*)d_in[13];
  const float* conv_w = (const float*)d_in[14];
  float* out = (float*)d_out;
  char* ws = (char*)d_ws;

  // ---- workspace layout (54.2 MB total) ----
  const size_t OFF_K     = 0;           // 25,690,112 B  bf16 k [16][8][3136][32]
  const size_t OFF_V     = 25690112;    // 25,690,112 B  bf16 vT [16][8][32][3136]
  const size_t OFF_YT    = OFF_K;       // bf16 Yt [16][256][3136], aliases dead k
  const size_t OFF_Z     = OFF_V;       // bf16 z  [16][256][3136], aliases dead v
  const size_t OFF_BQKV  = 51380224;    // 393,216 B
  const size_t OFF_WOT   = 51773440;    // 131,072 B
  const size_t OFF_BCONV = 51904512;    // 1,179,648 B
  const size_t OFF_PROJB = 53084160;    // 8,192 B
  const size_t OFF_CTXA  = 53092352;    // 2,097,152 B  fp32 [128][32] per bh
  const size_t OFF_KSUM  = 55189504;    // 65,536 B
  const size_t OFF_BN1S  = 55255040;    // 2,048 B
  const size_t OFF_BN2S  = 55257088;    // 2,048 B
  const size_t OFF_SC1   = 55259136;    // 2,048 B
  const size_t OFF_SC2   = 55261184;    // 2,048 B
  const size_t OFF_CTXT  = 55263232;    // 1,572,864 B  bf16 [48][128] per bh
  const size_t WS_NEEDED = 56836096;

  if (ws_size < WS_NEEDED) {
    // clean, diagnosable numeric failure instead of an OOB container kill
    zero_kernel<<<2048, 256, 0, stream>>>(out, out_size);
    return;
  }

  short* qb    = (short*)d_out;          // q [16][8][3136][32] bf16, 51,380,224 B == d_out size
  short* kb    = (short*)(ws + OFF_K);
  short* vtb   = (short*)(ws + OFF_V);
  short* Ytb   = (short*)(ws + OFF_YT);
  short* zb    = (short*)(ws + OFF_Z);
  short* Bqkv  = (short*)(ws + OFF_BQKV);
  short* WoT   = (short*)(ws + OFF_WOT);
  short* Bconv = (short*)(ws + OFF_BCONV);
  short* projb = (short*)(ws + OFF_PROJB);
  float* ctxa  = (float*)(ws + OFF_CTXA);
  float* ksum  = (float*)(ws + OFF_KSUM);
  float* bn1s  = (float*)(ws + OFF_BN1S);
  float* bn2s  = (float*)(ws + OFF_BN2S);
  float* sc1   = (float*)(ws + OFF_SC1);
  float* sc2   = (float*)(ws + OFF_SC2);
  short* ctxT  = (short*)(ws + OFF_CTXT);

  // zero: ctx_acc + ksum + bn1 sums + bn2 sums (contiguous)
  zero_kernel<<<512, 256, 0, stream>>>(ctxa, (2097152 + 65536 + 2048 + 2048) / 4);
  prep_kernel<<<256, 256, 0, stream>>>(Wq, Wk, Wv, Wo, proj, conv_w, Bqkv, WoT, Bconv, projb);
  bn_stats_kernel<<<4096, 256, 0, stream>>>(x, bn1s);
  bn_final_kernel<<<1, 256, 0, stream>>>(bn1s, bn1_g, bn1_b, sc1);
  qkv_gemm<<<dim3(392, 6), 256, 0, stream>>>(x, sc1, Bqkv, bq, bk, bv, qb, kb, vtb);
  attn_phase1<<<256, 256, 0, stream>>>(kb, vtb, projb, ctxa, ksum);
  ctx_finalize<<<128, 256, 0, stream>>>(ctxa, ksum, ctxT);
  attn_phase2<<<256, 256, 0, stream>>>(qb, ctxT, projb, Ytb);
  wo_gemm<<<dim3(392, 2), 256, 0, stream>>>(Ytb, WoT, bo, x, zb);
  bn_stats_bf16_kernel<<<4096, 256, 0, stream>>>(zb, bn2s);
  bn_final_kernel<<<1, 256, 0, stream>>>(bn2s, bn2_g, bn2_b, sc2);
  conv_gemm<<<dim3(392, 2), 256, 0, stream>>>(zb, sc2, Bconv, x, out);
}

// Round 4
// 655.873 us; speedup vs baseline: 1.6628x; 1.6628x over previous
//
#include <hip/hip_runtime.h>

// ---------------------------------------------------------------------------
// ACBlock: BN1+ReLU -> Performer attention -> +x -> BN2+ReLU -> conv3x3 -> +x
// B=16 C=256 H=W=56  S=3136 tokens/batch, NTOK=50176, heads=8, d=32, m=110
// Round 4: NHWC bf16 activation layouts everywhere -> all GEMM A-staging is
// pure 16B vector copies; M=64 tiles (32 KiB LDS) for occupancy.
// d_out doubles as scratch: [q | u1/xh]; conv fully overwrites d_out at the end.
// ---------------------------------------------------------------------------

typedef short short8 __attribute__((ext_vector_type(8)));
typedef float f32x4 __attribute__((ext_vector_type(4)));

#define DEVI static __device__ __forceinline__

#define CDIM 256
#define SDIM 3136
#define NTOK 50176
#define NHEAD 8
#define DHEAD 32
#define MFEAT 110
#define NORMC 0.42044820762685725f  // 32^-0.25
#define NPIX 50176.0f

DEVI unsigned short f2bf(float f) {
  union { float f; unsigned u; } v; v.f = f;
  unsigned r = v.u + 0x7fffu + ((v.u >> 16) & 1u);
  return (unsigned short)(r >> 16);
}

DEVI float bf2f(short h) {
  union { unsigned u; float f; } v;
  v.u = ((unsigned)(unsigned short)h) << 16;
  return v.f;
}

DEVI f32x4 mfma16(short8 a, short8 b, f32x4 c) {
  return __builtin_amdgcn_mfma_f32_16x16x32_bf16(a, b, c, 0, 0, 0);
}

DEVI unsigned long long pack4(const unsigned short* h) {
  return (unsigned long long)(h[0] | ((unsigned)h[1] << 16)) |
         ((unsigned long long)(h[2] | ((unsigned)h[3] << 16)) << 32);
}

// ---------------------------------------------------------------------------
__global__ void zero_kernel(float* p, int n) {
  for (int i = blockIdx.x * blockDim.x + threadIdx.x; i < n; i += gridDim.x * blockDim.x)
    p[i] = 0.f;
}

// Build bf16 B-operands: Bqkv[768][256] (= [sel*256+cout][cin]), WoT[256][256],
// Bconv[256][2304] (= [oc][off*256+cin]), projb[128][32] (norm folded, rows>=110 zero)
__global__ void prep_kernel(const float* __restrict__ Wq, const float* __restrict__ Wk,
                            const float* __restrict__ Wv, const float* __restrict__ Wo,
                            const float* __restrict__ proj, const float* __restrict__ conv_w,
                            short* __restrict__ Bqkv, short* __restrict__ WoT,
                            short* __restrict__ Bconv, short* __restrict__ projb) {
  const int t0 = blockIdx.x * blockDim.x + threadIdx.x;
  const int stride = gridDim.x * blockDim.x;
  for (int idx = t0; idx < 768 * 256; idx += stride) {
    const int n = idx >> 8, k = idx & 255;
    const float* W = (n < 256) ? Wq : ((n < 512) ? Wk : Wv);
    Bqkv[idx] = (short)f2bf(W[k * 256 + (n & 255)]);
  }
  for (int idx = t0; idx < 256 * 256; idx += stride) {
    const int oc = idx >> 8, k = idx & 255;
    WoT[idx] = (short)f2bf(Wo[k * 256 + oc]);
  }
  for (int idx = t0; idx < 256 * 2304; idx += stride) {
    const int oc = idx / 2304, r = idx - oc * 2304;
    const int off = r >> 8, c = r & 255;
    Bconv[idx] = (short)f2bf(conv_w[(oc * 256 + c) * 9 + off]);
  }
  for (int idx = t0; idx < 128 * 32; idx += stride) {
    const int row = idx >> 5, kk = idx & 31;
    const float v = (row < MFEAT) ? proj[row * 32 + kk] * NORMC : 0.f;
    projb[idx] = (short)f2bf(v);
  }
}

// per-channel sum / sumsq over (B,H,W) for NCHW fp32 x; grid = B*C blocks
__global__ void bn_stats_kernel(const float* __restrict__ src, float* __restrict__ sums) {
  const int c = blockIdx.x & 255, b = blockIdx.x >> 8;
  const float* p = src + ((size_t)b * CDIM + c) * SDIM;
  float s = 0.f, s2 = 0.f;
  for (int i = threadIdx.x; i < SDIM; i += 256) {
    const float v = p[i];
    s += v; s2 += v * v;
  }
  for (int o = 32; o > 0; o >>= 1) { s += __shfl_down(s, o); s2 += __shfl_down(s2, o); }
  __shared__ float ls[4], ls2[4];
  const int w = threadIdx.x >> 6;
  if ((threadIdx.x & 63) == 0) { ls[w] = s; ls2[w] = s2; }
  __syncthreads();
  if (threadIdx.x == 0) {
    s = ls[0] + ls[1] + ls[2] + ls[3];
    s2 = ls2[0] + ls2[1] + ls2[2] + ls2[3];
    atomicAdd(&sums[c], s);
    atomicAdd(&sums[256 + c], s2);
  }
}

// per-channel stats for NHWC bf16 z; grid = NTOK/64 blocks
__global__ void bn_stats_nhwc(const short* __restrict__ z, float* __restrict__ sums) {
  __shared__ float L[256][16];
  const int tid = threadIdx.x;
  const int cg = tid & 31, trow = tid >> 5;
  const size_t base = (size_t)blockIdx.x * 64 * 256;
  float s[8], s2[8];
#pragma unroll
  for (int j = 0; j < 8; ++j) { s[j] = 0.f; s2[j] = 0.f; }
#pragma unroll
  for (int i = 0; i < 8; ++i) {
    const int tok = trow + i * 8;
    const short8 v = *(const short8*)&z[base + (size_t)tok * 256 + cg * 8];
#pragma unroll
    for (int j = 0; j < 8; ++j) { const float f = bf2f(v[j]); s[j] += f; s2[j] += f * f; }
  }
#pragma unroll
  for (int j = 0; j < 8; ++j) { L[tid][j] = s[j]; L[tid][8 + j] = s2[j]; }
  __syncthreads();
  const int c = tid, cgi = c >> 3, j = c & 7;
  float a = 0.f, b2 = 0.f;
#pragma unroll
  for (int tr = 0; tr < 8; ++tr) { a += L[tr * 32 + cgi][j]; b2 += L[tr * 32 + cgi][8 + j]; }
  atomicAdd(&sums[c], a);
  atomicAdd(&sums[256 + c], b2);
}

__global__ void bn_final_kernel(const float* __restrict__ sums, const float* __restrict__ gamma,
                                const float* __restrict__ beta, float* __restrict__ scsh) {
  const int c = threadIdx.x;
  const float mean = sums[c] * (1.f / NPIX);
  const float var = sums[256 + c] * (1.f / NPIX) - mean * mean;
  const float sc = gamma[c] * rsqrtf(var + 1e-5f);
  scsh[c] = sc;
  scsh[256 + c] = beta[c] - mean * sc;
}

// ---------------------------------------------------------------------------
// x NCHW f32 -> dst NHWC bf16; mode=1 applies relu(bn1) using scsh.
// grid (NTOK/64, 4), 256 thr.
__global__ void transpose_x(const float* __restrict__ x, const float* __restrict__ scsh,
                            short* __restrict__ dst, int mode) {
  __shared__ short T[64][72];
  const int t0 = blockIdx.x * 64;
  const int b = t0 / SDIM;  // 64 | 3136 -> tile stays in one batch
  const int s0 = t0 - b * SDIM;
  const int c0 = blockIdx.y * 64;
  const int tid = threadIdx.x;
  const int tokl = tid & 63, cl = tid >> 6;
  const float* xb = x + ((size_t)b * CDIM + c0) * SDIM + s0;
#pragma unroll
  for (int i = 0; i < 16; ++i) {
    const int c = i * 4 + cl;
    float v = xb[(size_t)c * SDIM + tokl];
    if (mode) v = fmaxf(v * scsh[c0 + c] + scsh[256 + c0 + c], 0.f);
    T[c][tokl] = (short)f2bf(v);
  }
  __syncthreads();
#pragma unroll
  for (int j = 0; j < 2; ++j) {
    const int idx = tid + j * 256;  // 0..511
    const int tk = idx >> 3, ch8 = idx & 7;
    unsigned short h[8];
#pragma unroll
    for (int jj = 0; jj < 8; ++jj) h[jj] = (unsigned short)T[ch8 * 8 + jj][tk];
    unsigned long long* p = (unsigned long long*)&dst[(size_t)(t0 + tk) * 256 + c0 + ch8 * 8];
    p[0] = pack4(h);
    p[1] = pack4(h + 4);
  }
}

// u2 = relu(bn2(z))  (NHWC bf16 elementwise)
__global__ void u2_kernel(const short* __restrict__ z, const float* __restrict__ scsh,
                          short* __restrict__ u2) {
  const int nchunks = NTOK * 32;
  for (int idx = blockIdx.x * blockDim.x + threadIdx.x; idx < nchunks;
       idx += gridDim.x * blockDim.x) {
    const int cch = idx & 31;
    const short8 v = *(const short8*)&z[(size_t)idx * 8];
    unsigned short h[8];
#pragma unroll
    for (int j = 0; j < 8; ++j) {
      const int c = cch * 8 + j;
      h[j] = f2bf(fmaxf(bf2f(v[j]) * scsh[c] + scsh[256 + c], 0.f));
    }
    unsigned long long* p = (unsigned long long*)&u2[(size_t)idx * 8];
    p[0] = pack4(h);
    p[1] = pack4(h + 4);
  }
}

// ---------------------------------------------------------------------------
// QKV GEMM (M=64): A = u1 NHWC bf16 (pure copy staging), B = Bqkv[col][cin].
// Writes q,k as [b][h][s][d] bf16; v transposed as [b][h][d][s] bf16.
__global__ __launch_bounds__(256, 4)
void qkv_gemm(const short* __restrict__ u1, const short* __restrict__ BT,
              const float* __restrict__ bq, const float* __restrict__ bk,
              const float* __restrict__ bv,
              short* __restrict__ qo, short* __restrict__ ko, short* __restrict__ vo) {
  __shared__ short A_s[64 * 256];  // [tok][cin], 16B-granule xor swizzle
  const int tid = threadIdx.x;
  const int mtile = blockIdx.x, ntile = blockIdx.y;
  const int token0 = mtile * 64;
  {
    const int trow = tid >> 5, cch = tid & 31;
    const short* src = u1 + (size_t)token0 * 256;
#pragma unroll
    for (int i = 0; i < 8; ++i) {
      const int tok = trow + i * 8;
      const short8 vv = *(const short8*)&src[tok * 256 + cch * 8];
      const int phys = cch ^ (tok & 31);
      *(short8*)&A_s[tok * 256 + phys * 8] = vv;
    }
  }
  __syncthreads();

  const int lane = tid & 63, wv = tid >> 6;
  const int wm = wv & 1, wn = wv >> 1;
  const int quad = lane >> 4, l15 = lane & 15;
  const f32x4 vzero = {0.f, 0.f, 0.f, 0.f};
  f32x4 acc[2][4];
#pragma unroll
  for (int i = 0; i < 2; ++i)
#pragma unroll
    for (int j = 0; j < 4; ++j) acc[i][j] = vzero;
  const short* Bb = BT + (size_t)(ntile * 128 + wn * 64 + l15) * 256;
#pragma unroll
  for (int ks = 0; ks < 8; ++ks) {
    short8 af[2], bfr[4];
#pragma unroll
    for (int rf = 0; rf < 2; ++rf) {
      const int row = wm * 32 + rf * 16 + l15;
      const int phys = (ks * 4 + quad) ^ (row & 31);
      af[rf] = *(const short8*)&A_s[row * 256 + phys * 8];
    }
#pragma unroll
    for (int cf = 0; cf < 4; ++cf)
      bfr[cf] = *(const short8*)&Bb[cf * 16 * 256 + ks * 32 + quad * 8];
#pragma unroll
    for (int rf = 0; rf < 2; ++rf)
#pragma unroll
      for (int cf = 0; cf < 4; ++cf)
        acc[rf][cf] = mfma16(af[rf], bfr[cf], acc[rf][cf]);
  }

  const int sel = ntile >> 1;  // 0=q 1=k 2=v
  const int bb = token0 / SDIM;
#pragma unroll
  for (int cf = 0; cf < 4; ++cf) {
    const int col = ntile * 128 + wn * 64 + cf * 16 + l15;
    const int chn = col & 255, head = chn >> 5, dd = chn & 31;
    const float bias = (sel == 0) ? bq[chn] : ((sel == 1) ? bk[chn] : bv[chn]);
#pragma unroll
    for (int rf = 0; rf < 2; ++rf) {
      const int tokb = token0 + wm * 32 + rf * 16 + quad * 4;
      const int ss = tokb - bb * SDIM;
      if (sel < 2) {
        short* dst = (sel == 0) ? qo : ko;
        short* p = dst + ((size_t)(bb * NHEAD + head) * SDIM) * DHEAD + dd;
#pragma unroll
        for (int r = 0; r < 4; ++r)
          p[(size_t)(ss + r) * DHEAD] = (short)f2bf(acc[rf][cf][r] + bias);
      } else {
        unsigned short h4[4];
#pragma unroll
        for (int r = 0; r < 4; ++r) h4[r] = f2bf(acc[rf][cf][r] + bias);
        *(unsigned long long*)(vo + ((size_t)(bb * NHEAD + head) * DHEAD + dd) * SDIM + ss) = pack4(h4);
      }
    }
  }
}

// ---------------------------------------------------------------------------
// Phase 1: per (b,h): phi_k = relu(k @ projb^T)+eps via MFMA (K=32),
// LDS round-trip [mf][tok], then ctx[mf][d] += phi_k^T @ v, ksum[mf] += sums.
__global__ __launch_bounds__(256, 2)
void attn_phase1(const short* __restrict__ kk, const short* __restrict__ vt,
                 const short* __restrict__ projb, float* __restrict__ ctx_acc,
                 float* __restrict__ ksum) {
  __shared__ short proj_s[128 * 40];
  __shared__ short phi_s[4][128 * 40];
  const int tid = threadIdx.x;
  const int bh = blockIdx.x >> 1, halfI = blockIdx.x & 1;
  for (int i = tid; i < 128 * 32; i += 256)
    proj_s[(i >> 5) * 40 + (i & 31)] = projb[i];
  __syncthreads();
  const int lane = tid & 63, wv = tid >> 6;
  const int quad = lane >> 4, l15 = lane & 15;
  const short* kb = kk + (size_t)bh * SDIM * DHEAD;
  const short* vb = vt + (size_t)bh * DHEAD * SDIM;
  short* myphi = phi_s[wv];
  const f32x4 vzero = {0.f, 0.f, 0.f, 0.f};
  f32x4 cacc[8][2];
  float ks_acc[8];
#pragma unroll
  for (int i = 0; i < 8; ++i) { cacc[i][0] = vzero; cacc[i][1] = vzero; ks_acc[i] = 0.f; }

  for (int ch = halfI * 4 + wv; ch < 98; ch += 8) {
    const int tok0 = ch * 32;
    short8 afr[2];
    afr[0] = *(const short8*)&kb[(size_t)(tok0 + l15) * DHEAD + quad * 8];
    afr[1] = *(const short8*)&kb[(size_t)(tok0 + 16 + l15) * DHEAD + quad * 8];
#pragma unroll
    for (int cf = 0; cf < 8; ++cf) {
      const short8 bfr = *(const short8*)&proj_s[(cf * 16 + l15) * 40 + quad * 8];
      const float epsv = (cf < 6) ? 1e-3f : ((cf == 6) ? ((l15 < 14) ? 1e-3f : 0.f) : 0.f);
#pragma unroll
      for (int fr = 0; fr < 2; ++fr) {
        f32x4 p = mfma16(afr[fr], bfr, vzero);
        unsigned short h4[4];
        float srow = 0.f;
#pragma unroll
        for (int r = 0; r < 4; ++r) {
          const float pv = fmaxf(p[r], 0.f) + epsv;
          srow += pv;
          h4[r] = f2bf(pv);
        }
        ks_acc[cf] += srow;
        *(unsigned long long*)&myphi[(cf * 16 + l15) * 40 + fr * 16 + quad * 4] = pack4(h4);
      }
    }
    short8 bv2[2];
    bv2[0] = *(const short8*)&vb[(size_t)l15 * SDIM + tok0 + quad * 8];
    bv2[1] = *(const short8*)&vb[(size_t)(16 + l15) * SDIM + tok0 + quad * 8];
#pragma unroll
    for (int mfr = 0; mfr < 8; ++mfr) {
      const short8 a2 = *(const short8*)&myphi[(mfr * 16 + l15) * 40 + quad * 8];
      cacc[mfr][0] = mfma16(a2, bv2[0], cacc[mfr][0]);
      cacc[mfr][1] = mfma16(a2, bv2[1], cacc[mfr][1]);
    }
  }
#pragma unroll
  for (int cf = 0; cf < 8; ++cf) {
    float v = ks_acc[cf];
    v += __shfl_xor(v, 16);
    v += __shfl_xor(v, 32);
    if (lane < 16) atomicAdd(&ksum[bh * 128 + cf * 16 + lane], v);
  }
  float* cb = ctx_acc + (size_t)bh * 4096;
#pragma unroll
  for (int mfr = 0; mfr < 8; ++mfr)
#pragma unroll
    for (int df = 0; df < 2; ++df)
#pragma unroll
      for (int r = 0; r < 4; ++r)
        atomicAdd(&cb[(mfr * 16 + quad * 4 + r) * 32 + df * 16 + l15], cacc[mfr][df][r]);
}

// ctx_T[bh][48][128] bf16: rows 0..31 = ctx^T (d-major), row 32 = ksum, 33..47 = 0
__global__ void ctx_finalize(const float* __restrict__ ctx_acc, const float* __restrict__ ksum,
                             short* __restrict__ ctx_T) {
  const int bh = blockIdx.x;
  const float* ca = ctx_acc + (size_t)bh * 4096;
  const float* ks = ksum + bh * 128;
  short* ct = ctx_T + (size_t)bh * 48 * 128;
  for (int i = threadIdx.x; i < 48 * 128; i += 256) {
    const int row = i >> 7, mf = i & 127;
    const float v = (row < 32) ? ca[mf * 32 + row] : ((row == 32) ? ks[mf] : 0.f);
    ct[i] = (short)f2bf(v);
  }
}

// Phase 2: phi_q via MFMA, out = phi_q@ctx * 1/denom; writes Y NHWC bf16
// via per-wave LDS transpose.
__global__ __launch_bounds__(256, 2)
void attn_phase2(const short* __restrict__ qq, const short* __restrict__ ctx_T,
                 const short* __restrict__ projb, short* __restrict__ Yn) {
  __shared__ short proj_s[128 * 40];
  __shared__ short ctx_s[48 * 136];
  __shared__ short phi_s[4][32 * 136];
  const int tid = threadIdx.x;
  const int bh = blockIdx.x >> 1, halfI = blockIdx.x & 1;
  for (int i = tid; i < 128 * 32; i += 256)
    proj_s[(i >> 5) * 40 + (i & 31)] = projb[i];
  {
    const short* ct = ctx_T + (size_t)bh * 48 * 128;
    for (int i = tid; i < 48 * 128; i += 256)
      ctx_s[(i >> 7) * 136 + (i & 127)] = ct[i];
  }
  __syncthreads();
  const int lane = tid & 63, wv = tid >> 6;
  const int quad = lane >> 4, l15 = lane & 15;
  const int b = bh >> 3, head = bh & 7;
  const short* qb = qq + (size_t)bh * SDIM * DHEAD;
  short* myphi = phi_s[wv];
  const f32x4 vzero = {0.f, 0.f, 0.f, 0.f};

  for (int ch = halfI * 4 + wv; ch < 98; ch += 8) {
    const int tok0 = ch * 32;
    short8 afr[2];
    afr[0] = *(const short8*)&qb[(size_t)(tok0 + l15) * DHEAD + quad * 8];
    afr[1] = *(const short8*)&qb[(size_t)(tok0 + 16 + l15) * DHEAD + quad * 8];
#pragma unroll
    for (int cf = 0; cf < 8; ++cf) {
      const short8 bfr = *(const short8*)&proj_s[(cf * 16 + l15) * 40 + quad * 8];
      const float epsv = (cf < 6) ? 1e-3f : ((cf == 6) ? ((l15 < 14) ? 1e-3f : 0.f) : 0.f);
#pragma unroll
      for (int fr = 0; fr < 2; ++fr) {
        f32x4 p = mfma16(afr[fr], bfr, vzero);
#pragma unroll
        for (int r = 0; r < 4; ++r) {
          const float pv = fmaxf(p[r], 0.f) + epsv;
          myphi[(fr * 16 + quad * 4 + r) * 136 + cf * 16 + l15] = (short)f2bf(pv);
        }
      }
    }
    f32x4 oacc[2][3];
#pragma unroll
    for (int fr = 0; fr < 2; ++fr)
#pragma unroll
      for (int c3 = 0; c3 < 3; ++c3) oacc[fr][c3] = vzero;
#pragma unroll
    for (int ksI = 0; ksI < 4; ++ksI) {
      short8 a3[2];
      a3[0] = *(const short8*)&myphi[l15 * 136 + ksI * 32 + quad * 8];
      a3[1] = *(const short8*)&myphi[(16 + l15) * 136 + ksI * 32 + quad * 8];
#pragma unroll
      for (int c3 = 0; c3 < 3; ++c3) {
        const short8 b3 = *(const short8*)&ctx_s[(c3 * 16 + l15) * 136 + ksI * 32 + quad * 8];
        oacc[0][c3] = mfma16(a3[0], b3, oacc[0][c3]);
        oacc[1][c3] = mfma16(a3[1], b3, oacc[1][c3]);
      }
    }
    // transpose 32tok x 32d through wave-private LDS (pitch 40 -> 16B aligned rows)
#pragma unroll
    for (int fr = 0; fr < 2; ++fr) {
      float dinv[4];
#pragma unroll
      for (int r = 0; r < 4; ++r) {
        const float den = __shfl(oacc[fr][2][r], quad << 4);
        dinv[r] = 1.f / den;
      }
#pragma unroll
      for (int c3 = 0; c3 < 2; ++c3)
#pragma unroll
        for (int r = 0; r < 4; ++r)
          myphi[(fr * 16 + quad * 4 + r) * 40 + c3 * 16 + l15] =
              (short)f2bf(oacc[fr][c3][r] * dinv[r]);
    }
    const size_t trow0 = (size_t)(b * SDIM + tok0) * 256 + head * 32;
#pragma unroll
    for (int it = 0; it < 2; ++it) {
      const int idx = it * 64 + lane;
      const int tl = idx >> 2, c4 = idx & 3;
      const short8 vv = *(const short8*)&myphi[tl * 40 + c4 * 8];
      *(short8*)&Yn[trow0 + (size_t)tl * 256 + c4 * 8] = vv;
    }
  }
}

// ---------------------------------------------------------------------------
// Wo GEMM (M=64): A = Y NHWC bf16, z = Y@Wo + bo + xh (NHWC bf16) via LDS transpose.
__global__ __launch_bounds__(256, 4)
void wo_gemm(const short* __restrict__ Yn, const short* __restrict__ WoT,
             const float* __restrict__ bo, const short* __restrict__ xh,
             short* __restrict__ z) {
  __shared__ short A_s[64 * 256];  // 32 KiB; reused as zt[64][136] in epilogue
  const int tid = threadIdx.x;
  const int mtile = blockIdx.x, ntile = blockIdx.y;
  const int token0 = mtile * 64;
  {
    const int trow = tid >> 5, cch = tid & 31;
    const short* src = Yn + (size_t)token0 * 256;
#pragma unroll
    for (int i = 0; i < 8; ++i) {
      const int tok = trow + i * 8;
      const short8 vv = *(const short8*)&src[tok * 256 + cch * 8];
      const int phys = cch ^ (tok & 31);
      *(short8*)&A_s[tok * 256 + phys * 8] = vv;
    }
  }
  __syncthreads();

  const int lane = tid & 63, wv = tid >> 6;
  const int wm = wv & 1, wn = wv >> 1;
  const int quad = lane >> 4, l15 = lane & 15;
  const f32x4 vzero = {0.f, 0.f, 0.f, 0.f};
  f32x4 acc[2][4];
#pragma unroll
  for (int i = 0; i < 2; ++i)
#pragma unroll
    for (int j = 0; j < 4; ++j) acc[i][j] = vzero;
  const short* Bb = WoT + (size_t)(ntile * 128 + wn * 64 + l15) * 256;
#pragma unroll
  for (int ks = 0; ks < 8; ++ks) {
    short8 af[2], bfr[4];
#pragma unroll
    for (int rf = 0; rf < 2; ++rf) {
      const int row = wm * 32 + rf * 16 + l15;
      const int phys = (ks * 4 + quad) ^ (row & 31);
      af[rf] = *(const short8*)&A_s[row * 256 + phys * 8];
    }
#pragma unroll
    for (int cf = 0; cf < 4; ++cf)
      bfr[cf] = *(const short8*)&Bb[cf * 16 * 256 + ks * 32 + quad * 8];
#pragma unroll
    for (int rf = 0; rf < 2; ++rf)
#pragma unroll
      for (int cf = 0; cf < 4; ++cf)
        acc[rf][cf] = mfma16(af[rf], bfr[cf], acc[rf][cf]);
  }
  // epilogue: C-frag -> LDS [tok][oc] (bias fused), then coalesced NHWC rows (+xh)
  __syncthreads();
  short* zt = A_s;
#pragma unroll
  for (int cf = 0; cf < 4; ++cf) {
    const int ocl = wn * 64 + cf * 16 + l15;
    const float bias = bo[ntile * 128 + ocl];
#pragma unroll
    for (int rf = 0; rf < 2; ++rf) {
      const int tl = wm * 32 + rf * 16 + quad * 4;
#pragma unroll
      for (int r = 0; r < 4; ++r)
        zt[(tl + r) * 136 + ocl] = (short)f2bf(acc[rf][cf][r] + bias);
    }
  }
  __syncthreads();
#pragma unroll
  for (int j = 0; j < 4; ++j) {
    const int idx = tid + j * 256;  // 0..1023
    const int tl = idx >> 4, ch = idx & 15;
    const short8 zv = *(const short8*)&zt[tl * 136 + ch * 8];
    const size_t gbase = (size_t)(token0 + tl) * 256 + ntile * 128 + ch * 8;
    const short8 xv = *(const short8*)&xh[gbase];
    unsigned short h[8];
#pragma unroll
    for (int jj = 0; jj < 8; ++jj) h[jj] = f2bf(bf2f(zv[jj]) + bf2f(xv[jj]));
    unsigned long long* p = (unsigned long long*)&z[gbase];
    p[0] = pack4(h);
    p[1] = pack4(h + 4);
  }
}

// ---------------------------------------------------------------------------
// Conv 3x3 implicit GEMM (M=64): A = u2 NHWC bf16 patches (pure vector staging),
// B = Bconv[oc][off*256+cin]. Epilogue adds residual x (NCHW f32), writes out NCHW f32.
__global__ __launch_bounds__(256, 4)
void conv_gemm(const short* __restrict__ u2, const short* __restrict__ Bc,
               const float* __restrict__ x, float* __restrict__ out) {
  __shared__ short A_s[64 * 256];
  const int tid = threadIdx.x;
  const int mtile = blockIdx.x, ntile = blockIdx.y;
  const int bb = mtile / 49, s0 = (mtile - bb * 49) * 64;
  const short* ub = u2 + (size_t)bb * SDIM * 256;
  const int trow = tid >> 5, cch = tid & 31;
  const int lane = tid & 63, wv = tid >> 6;
  const int wm = wv & 1, wn = wv >> 1;
  const int quad = lane >> 4, l15 = lane & 15;
  const f32x4 vzero = {0.f, 0.f, 0.f, 0.f};
  f32x4 acc[2][4];
#pragma unroll
  for (int i = 0; i < 2; ++i)
#pragma unroll
    for (int j = 0; j < 4; ++j) acc[i][j] = vzero;

  for (int off = 0; off < 9; ++off) {
    const int dy = off / 3 - 1, dx = off - (off / 3) * 3 - 1;
    __syncthreads();
#pragma unroll
    for (int i = 0; i < 8; ++i) {
      const int tok = trow + i * 8;
      const int s = s0 + tok;
      const int yy = s / 56, xx = s - yy * 56;
      const int ny = yy + dy, nx = xx + dx;
      short8 vv = {0, 0, 0, 0, 0, 0, 0, 0};
      if (((unsigned)ny < 56u) && ((unsigned)nx < 56u))
        vv = *(const short8*)&ub[(size_t)(ny * 56 + nx) * 256 + cch * 8];
      const int phys = cch ^ (tok & 31);
      *(short8*)&A_s[tok * 256 + phys * 8] = vv;
    }
    __syncthreads();
    const short* Bb = Bc + (size_t)(ntile * 128 + wn * 64 + l15) * 2304 + off * 256;
#pragma unroll
    for (int ks = 0; ks < 8; ++ks) {
      short8 af[2], bfr[4];
#pragma unroll
      for (int rf = 0; rf < 2; ++rf) {
        const int row = wm * 32 + rf * 16 + l15;
        const int phys = (ks * 4 + quad) ^ (row & 31);
        af[rf] = *(const short8*)&A_s[row * 256 + phys * 8];
      }
#pragma unroll
      for (int cf = 0; cf < 4; ++cf)
        bfr[cf] = *(const short8*)&Bb[(size_t)cf * 16 * 2304 + ks * 32 + quad * 8];
#pragma unroll
      for (int rf = 0; rf < 2; ++rf)
#pragma unroll
        for (int cf = 0; cf < 4; ++cf)
          acc[rf][cf] = mfma16(af[rf], bfr[cf], acc[rf][cf]);
    }
  }
#pragma unroll
  for (int cf = 0; cf < 4; ++cf) {
    const int oc = ntile * 128 + wn * 64 + cf * 16 + l15;
#pragma unroll
    for (int rf = 0; rf < 2; ++rf) {
      const int ss = s0 + wm * 32 + rf * 16 + quad * 4;
      const size_t base = ((size_t)(bb * CDIM + oc)) * SDIM + ss;
      const f32x4 xv = *(const f32x4*)(x + base);
      f32x4 res;
#pragma unroll
      for (int r = 0; r < 4; ++r) res[r] = acc[rf][cf][r] + xv[r];
      *(f32x4*)(out + base) = res;
    }
  }
}

// ---------------------------------------------------------------------------
extern "C" void kernel_launch(void* const* d_in, const int* in_sizes, int n_in,
                              void* d_out, int out_size, void* d_ws, size_t ws_size,
                              hipStream_t stream) {
  const float* x      = (const float*)d_in[0];
  const float* bn1_g  = (const float*)d_in[1];
  const float* bn1_b  = (const float*)d_in[2];
  const float* bn2_g  = (const float*)d_in[3];
  const float* bn2_b  = (const float*)d_in[4];
  const float* Wq     = (const float*)d_in[5];
  const float* bq     = (const float*)d_in[6];
  const float* Wk     = (const float*)d_in[7];
  const float* bk     = (const float*)d_in[8];
  const float* Wv     = (const float*)d_in[9];
  const float* bv     = (const float*)d_in[10];
  const float* Wo     = (const float*)d_in[11];
  const float* bo     = (const float*)d_in[12];
  const float* proj   = (const float*)d_in[13];
  const float* conv_w = (const float*)d_in[14];
  float* out = (float*)d_out;
  char* ws = (char*)d_ws;

  // ---- workspace layout (unchanged guard; 54.2 MB) ----
  const size_t OFF_K     = 0;           // bf16 k [16][8][3136][32]; then Y NHWC; then u2
  const size_t OFF_V     = 25690112;    // bf16 vT [16][8][32][3136]; then z NHWC
  const size_t OFF_BQKV  = 51380224;    // 393,216 B
  const size_t OFF_WOT   = 51773440;    // 131,072 B
  const size_t OFF_BCONV = 51904512;    // 1,179,648 B
  const size_t OFF_PROJB = 53084160;    // 8,192 B
  const size_t OFF_CTXA  = 53092352;    // 2,097,152 B
  const size_t OFF_KSUM  = 55189504;    // 65,536 B
  const size_t OFF_BN1S  = 55255040;    // 2,048 B
  const size_t OFF_BN2S  = 55257088;    // 2,048 B
  const size_t OFF_SC1   = 55259136;    // 2,048 B
  const size_t OFF_SC2   = 55261184;    // 2,048 B
  const size_t OFF_CTXT  = 55263232;    // 1,572,864 B
  const size_t WS_NEEDED = 56836096;

  if (ws_size < WS_NEEDED) {
    zero_kernel<<<2048, 256, 0, stream>>>(out, out_size);
    return;
  }

  // d_out doubles as scratch: [q (25.7MB) | u1 then xh (25.7MB)]
  short* qb    = (short*)d_out;
  short* half2 = (short*)d_out + (size_t)NTOK * DHEAD * NHEAD / 2 * 0 + 12845056;  // element offset
  short* kb    = (short*)(ws + OFF_K);
  short* vtb   = (short*)(ws + OFF_V);
  short* Yn    = (short*)(ws + OFF_K);  // aliases dead k (after phase1)
  short* zbuf  = (short*)(ws + OFF_V);  // aliases dead vT (after phase1)
  short* u2b   = (short*)(ws + OFF_K);  // aliases dead Y (after wo)
  short* Bqkv  = (short*)(ws + OFF_BQKV);
  short* WoT   = (short*)(ws + OFF_WOT);
  short* Bconv = (short*)(ws + OFF_BCONV);
  short* projb = (short*)(ws + OFF_PROJB);
  float* ctxa  = (float*)(ws + OFF_CTXA);
  float* ksum  = (float*)(ws + OFF_KSUM);
  float* bn1s  = (float*)(ws + OFF_BN1S);
  float* bn2s  = (float*)(ws + OFF_BN2S);
  float* sc1   = (float*)(ws + OFF_SC1);
  float* sc2   = (float*)(ws + OFF_SC2);
  short* ctxT  = (short*)(ws + OFF_CTXT);

  zero_kernel<<<512, 256, 0, stream>>>(ctxa, (2097152 + 65536 + 2048 + 2048) / 4);
  prep_kernel<<<256, 256, 0, stream>>>(Wq, Wk, Wv, Wo, proj, conv_w, Bqkv, WoT, Bconv, projb);
  bn_stats_kernel<<<4096, 256, 0, stream>>>(x, bn1s);
  bn_final_kernel<<<1, 256, 0, stream>>>(bn1s, bn1_g, bn1_b, sc1);
  // u1 = relu(bn1(x)) NHWC bf16 in d_out second half
  transpose_x<<<dim3(784, 4), 256, 0, stream>>>(x, sc1, half2, 1);
  qkv_gemm<<<dim3(784, 6), 256, 0, stream>>>(half2, Bqkv, bq, bk, bv, qb, kb, vtb);
  attn_phase1<<<256, 256, 0, stream>>>(kb, vtb, projb, ctxa, ksum);
  ctx_finalize<<<128, 256, 0, stream>>>(ctxa, ksum, ctxT);
  attn_phase2<<<256, 256, 0, stream>>>(qb, ctxT, projb, Yn);
  // xh = raw x NHWC bf16 (overwrites dead u1)
  transpose_x<<<dim3(784, 4), 256, 0, stream>>>(x, sc1, half2, 0);
  wo_gemm<<<dim3(784, 2), 256, 0, stream>>>(Yn, WoT, bo, half2, zbuf);
  bn_stats_nhwc<<<784, 256, 0, stream>>>(zbuf, bn2s);
  bn_final_kernel<<<1, 256, 0, stream>>>(bn2s, bn2_g, bn2_b, sc2);
  u2_kernel<<<1024, 256, 0, stream>>>(zbuf, sc2, u2b);
  conv_gemm<<<dim3(784, 2), 256, 0, stream>>>(u2b, Bconv, x, out);
}

// Round 5
// 577.164 us; speedup vs baseline: 1.8896x; 1.1364x over previous
//
#include <hip/hip_runtime.h>

// ---------------------------------------------------------------------------
// ACBlock: BN1+ReLU -> Performer attention -> +x -> BN2+ReLU -> conv3x3 -> +x
// B=16 C=256 H=W=56  S=3136 tokens/batch, NTOK=50176, heads=8, d=32, m=110
// Round 5: fragment-major packed B (coalesced 1KB B-frag loads), N=256 panels
// with 4-way wave N-split (B read once per block), conv staging prefetch.
// ---------------------------------------------------------------------------

typedef short short8 __attribute__((ext_vector_type(8)));
typedef float f32x4 __attribute__((ext_vector_type(4)));

#define DEVI static __device__ __forceinline__

#define CDIM 256
#define SDIM 3136
#define NTOK 50176
#define NHEAD 8
#define DHEAD 32
#define MFEAT 110
#define NORMC 0.42044820762685725f  // 32^-0.25
#define NPIX 50176.0f

DEVI unsigned short f2bf(float f) {
  union { float f; unsigned u; } v; v.f = f;
  unsigned r = v.u + 0x7fffu + ((v.u >> 16) & 1u);
  return (unsigned short)(r >> 16);
}

DEVI float bf2f(short h) {
  union { unsigned u; float f; } v;
  v.u = ((unsigned)(unsigned short)h) << 16;
  return v.f;
}

DEVI f32x4 mfma16(short8 a, short8 b, f32x4 c) {
  return __builtin_amdgcn_mfma_f32_16x16x32_bf16(a, b, c, 0, 0, 0);
}

DEVI unsigned long long pack4(const unsigned short* h) {
  return (unsigned long long)(h[0] | ((unsigned)h[1] << 16)) |
         ((unsigned long long)(h[2] | ((unsigned)h[3] << 16)) << 32);
}

// ---------------------------------------------------------------------------
__global__ void zero_kernel(float* p, int n) {
  for (int i = blockIdx.x * blockDim.x + threadIdx.x; i < n; i += gridDim.x * blockDim.x)
    p[i] = 0.f;
}

// Fragment-major packed B operands.
// Layout: packed[(ks*16 + nf)*512 + lane*8 + j] = B[n = nf*16 + (lane&15)]
//                                                  [k = ks*32 + (lane>>4)*8 + j]
// One wave fragment load (64 lanes x 16B) = 1024B contiguous -> fully coalesced.
__global__ void prep_kernel(const float* __restrict__ Wq, const float* __restrict__ Wk,
                            const float* __restrict__ Wv, const float* __restrict__ Wo,
                            const float* __restrict__ proj, const float* __restrict__ conv_w,
                            short* __restrict__ Bqkv, short* __restrict__ WoT,
                            short* __restrict__ Bconv, short* __restrict__ projb) {
  const int t0 = blockIdx.x * blockDim.x + threadIdx.x;
  const int stride = gridDim.x * blockDim.x;
  // Bqkv packed: [sel][ks][nf][lane][j], 3*65536 shorts. B[n][k] = W[k*256+n].
  for (int idx = t0; idx < 3 * 65536; idx += stride) {
    const int sel = idx >> 16, r = idx & 65535;
    const int ks = r >> 13, nf = (r >> 9) & 15, lane = (r >> 3) & 63, j = r & 7;
    const int n = nf * 16 + (lane & 15), k = ks * 32 + (lane >> 4) * 8 + j;
    const float* W = (sel == 0) ? Wq : ((sel == 1) ? Wk : Wv);
    Bqkv[idx] = (short)f2bf(W[k * 256 + n]);
  }
  // WoT packed: [ks][nf][lane][j], 65536 shorts. B[oc][cin] = Wo[cin*256+oc].
  for (int idx = t0; idx < 65536; idx += stride) {
    const int ks = idx >> 13, nf = (idx >> 9) & 15, lane = (idx >> 3) & 63, j = idx & 7;
    const int n = nf * 16 + (lane & 15), k = ks * 32 + (lane >> 4) * 8 + j;
    WoT[idx] = (short)f2bf(Wo[k * 256 + n]);
  }
  // Bconv packed: [off][ks][nf][lane][j], 9*65536 shorts.
  // B[oc][off*256+cin] = conv_w[(oc*256+cin)*9+off].
  for (int idx = t0; idx < 9 * 65536; idx += stride) {
    const int off = idx >> 16, r = idx & 65535;
    const int ks = r >> 13, nf = (r >> 9) & 15, lane = (r >> 3) & 63, j = r & 7;
    const int oc = nf * 16 + (lane & 15), cin = ks * 32 + (lane >> 4) * 8 + j;
    Bconv[idx] = (short)f2bf(conv_w[(oc * 256 + cin) * 9 + off]);
  }
  for (int idx = t0; idx < 128 * 32; idx += stride) {
    const int row = idx >> 5, kk = idx & 31;
    const float v = (row < MFEAT) ? proj[row * 32 + kk] * NORMC : 0.f;
    projb[idx] = (short)f2bf(v);
  }
}

// per-channel sum / sumsq over (B,H,W) for NCHW fp32 x; grid = B*C blocks
__global__ void bn_stats_kernel(const float* __restrict__ src, float* __restrict__ sums) {
  const int c = blockIdx.x & 255, b = blockIdx.x >> 8;
  const float* p = src + ((size_t)b * CDIM + c) * SDIM;
  float s = 0.f, s2 = 0.f;
  for (int i = threadIdx.x; i < SDIM; i += 256) {
    const float v = p[i];
    s += v; s2 += v * v;
  }
  for (int o = 32; o > 0; o >>= 1) { s += __shfl_down(s, o); s2 += __shfl_down(s2, o); }
  __shared__ float ls[4], ls2[4];
  const int w = threadIdx.x >> 6;
  if ((threadIdx.x & 63) == 0) { ls[w] = s; ls2[w] = s2; }
  __syncthreads();
  if (threadIdx.x == 0) {
    s = ls[0] + ls[1] + ls[2] + ls[3];
    s2 = ls2[0] + ls2[1] + ls2[2] + ls2[3];
    atomicAdd(&sums[c], s);
    atomicAdd(&sums[256 + c], s2);
  }
}

// per-channel stats for NHWC bf16 z; grid = NTOK/64 blocks
__global__ void bn_stats_nhwc(const short* __restrict__ z, float* __restrict__ sums) {
  __shared__ float L[256][16];
  const int tid = threadIdx.x;
  const int cg = tid & 31, trow = tid >> 5;
  const size_t base = (size_t)blockIdx.x * 64 * 256;
  float s[8], s2[8];
#pragma unroll
  for (int j = 0; j < 8; ++j) { s[j] = 0.f; s2[j] = 0.f; }
#pragma unroll
  for (int i = 0; i < 8; ++i) {
    const int tok = trow + i * 8;
    const short8 v = *(const short8*)&z[base + (size_t)tok * 256 + cg * 8];
#pragma unroll
    for (int j = 0; j < 8; ++j) { const float f = bf2f(v[j]); s[j] += f; s2[j] += f * f; }
  }
#pragma unroll
  for (int j = 0; j < 8; ++j) { L[tid][j] = s[j]; L[tid][8 + j] = s2[j]; }
  __syncthreads();
  const int c = tid, cgi = c >> 3, j = c & 7;
  float a = 0.f, b2 = 0.f;
#pragma unroll
  for (int tr = 0; tr < 8; ++tr) { a += L[tr * 32 + cgi][j]; b2 += L[tr * 32 + cgi][8 + j]; }
  atomicAdd(&sums[c], a);
  atomicAdd(&sums[256 + c], b2);
}

__global__ void bn_final_kernel(const float* __restrict__ sums, const float* __restrict__ gamma,
                                const float* __restrict__ beta, float* __restrict__ scsh) {
  const int c = threadIdx.x;
  const float mean = sums[c] * (1.f / NPIX);
  const float var = sums[256 + c] * (1.f / NPIX) - mean * mean;
  const float sc = gamma[c] * rsqrtf(var + 1e-5f);
  scsh[c] = sc;
  scsh[256 + c] = beta[c] - mean * sc;
}

// ---------------------------------------------------------------------------
// x NCHW f32 -> dst NHWC bf16; mode=1 applies relu(bn1) using scsh.
__global__ void transpose_x(const float* __restrict__ x, const float* __restrict__ scsh,
                            short* __restrict__ dst, int mode) {
  __shared__ short T[64][72];
  const int t0 = blockIdx.x * 64;
  const int b = t0 / SDIM;
  const int s0 = t0 - b * SDIM;
  const int c0 = blockIdx.y * 64;
  const int tid = threadIdx.x;
  const int tokl = tid & 63, cl = tid >> 6;
  const float* xb = x + ((size_t)b * CDIM + c0) * SDIM + s0;
#pragma unroll
  for (int i = 0; i < 16; ++i) {
    const int c = i * 4 + cl;
    float v = xb[(size_t)c * SDIM + tokl];
    if (mode) v = fmaxf(v * scsh[c0 + c] + scsh[256 + c0 + c], 0.f);
    T[c][tokl] = (short)f2bf(v);
  }
  __syncthreads();
#pragma unroll
  for (int j = 0; j < 2; ++j) {
    const int idx = tid + j * 256;
    const int tk = idx >> 3, ch8 = idx & 7;
    unsigned short h[8];
#pragma unroll
    for (int jj = 0; jj < 8; ++jj) h[jj] = (unsigned short)T[ch8 * 8 + jj][tk];
    unsigned long long* p = (unsigned long long*)&dst[(size_t)(t0 + tk) * 256 + c0 + ch8 * 8];
    p[0] = pack4(h);
    p[1] = pack4(h + 4);
  }
}

// u2 = relu(bn2(z))  (NHWC bf16 elementwise)
__global__ void u2_kernel(const short* __restrict__ z, const float* __restrict__ scsh,
                          short* __restrict__ u2) {
  const int nchunks = NTOK * 32;
  for (int idx = blockIdx.x * blockDim.x + threadIdx.x; idx < nchunks;
       idx += gridDim.x * blockDim.x) {
    const int cch = idx & 31;
    const short8 v = *(const short8*)&z[(size_t)idx * 8];
    unsigned short h[8];
#pragma unroll
    for (int j = 0; j < 8; ++j) {
      const int c = cch * 8 + j;
      h[j] = f2bf(fmaxf(bf2f(v[j]) * scsh[c] + scsh[256 + c], 0.f));
    }
    unsigned long long* p = (unsigned long long*)&u2[(size_t)idx * 8];
    p[0] = pack4(h);
    p[1] = pack4(h + 4);
  }
}

// ---------------------------------------------------------------------------
// QKV GEMM: M=64, N=256 per block (grid 784 x 3, blockIdx.y = sel 0=q/1=k/2=v).
// A = u1 NHWC bf16; B = Bqkv fragment-major packed. Per wave: rf=4, cf=4.
__global__ __launch_bounds__(256, 4)
void qkv_gemm(const short* __restrict__ u1, const short* __restrict__ BT,
              const float* __restrict__ bq, const float* __restrict__ bk,
              const float* __restrict__ bv,
              short* __restrict__ qo, short* __restrict__ ko, short* __restrict__ vo) {
  __shared__ short A_s[64 * 256];
  const int tid = threadIdx.x;
  const int mtile = blockIdx.x, sel = blockIdx.y;
  const int token0 = mtile * 64;
  {
    const int trow = tid >> 5, cch = tid & 31;
    const short* src = u1 + (size_t)token0 * 256;
#pragma unroll
    for (int i = 0; i < 8; ++i) {
      const int tok = trow + i * 8;
      const short8 vv = *(const short8*)&src[tok * 256 + cch * 8];
      const int phys = cch ^ (tok & 31);
      *(short8*)&A_s[tok * 256 + phys * 8] = vv;
    }
  }
  __syncthreads();

  const int lane = tid & 63, wv = tid >> 6;
  const int quad = lane >> 4, l15 = lane & 15;
  const f32x4 vzero = {0.f, 0.f, 0.f, 0.f};
  f32x4 acc[4][4];
#pragma unroll
  for (int i = 0; i < 4; ++i)
#pragma unroll
    for (int j = 0; j < 4; ++j) acc[i][j] = vzero;
  const short* Bp = BT + ((size_t)sel << 16);
#pragma unroll
  for (int ks = 0; ks < 8; ++ks) {
    short8 af[4], bfr[4];
#pragma unroll
    for (int rf = 0; rf < 4; ++rf) {
      const int row = rf * 16 + l15;
      const int phys = (ks * 4 + quad) ^ (row & 31);
      af[rf] = *(const short8*)&A_s[row * 256 + phys * 8];
    }
#pragma unroll
    for (int cf = 0; cf < 4; ++cf)
      bfr[cf] = *(const short8*)&Bp[((((ks << 4) | (wv << 2) | cf) << 6) | lane) << 3];
#pragma unroll
    for (int rf = 0; rf < 4; ++rf)
#pragma unroll
      for (int cf = 0; cf < 4; ++cf)
        acc[rf][cf] = mfma16(af[rf], bfr[cf], acc[rf][cf]);
  }

  const int bb = token0 / SDIM;
  const int s0 = token0 - bb * SDIM;
#pragma unroll
  for (int cf = 0; cf < 4; ++cf) {
    const int chn = wv * 64 + cf * 16 + l15;
    const int head = chn >> 5, dd = chn & 31;
    const float bias = (sel == 0) ? bq[chn] : ((sel == 1) ? bk[chn] : bv[chn]);
#pragma unroll
    for (int rf = 0; rf < 4; ++rf) {
      const int ss = s0 + rf * 16 + quad * 4;
      if (sel < 2) {
        short* dst = (sel == 0) ? qo : ko;
        short* p = dst + ((size_t)(bb * NHEAD + head) * SDIM) * DHEAD + dd;
#pragma unroll
        for (int r = 0; r < 4; ++r)
          p[(size_t)(ss + r) * DHEAD] = (short)f2bf(acc[rf][cf][r] + bias);
      } else {
        unsigned short h4[4];
#pragma unroll
        for (int r = 0; r < 4; ++r) h4[r] = f2bf(acc[rf][cf][r] + bias);
        *(unsigned long long*)(vo + ((size_t)(bb * NHEAD + head) * DHEAD + dd) * SDIM + ss) = pack4(h4);
      }
    }
  }
}

// ---------------------------------------------------------------------------
// Phase 1: per (b,h): phi_k = relu(k @ projb^T)+eps via MFMA (K=32),
// LDS round-trip [mf][tok], then ctx[mf][d] += phi_k^T @ v, ksum[mf] += sums.
__global__ __launch_bounds__(256, 2)
void attn_phase1(const short* __restrict__ kk, const short* __restrict__ vt,
                 const short* __restrict__ projb, float* __restrict__ ctx_acc,
                 float* __restrict__ ksum) {
  __shared__ short proj_s[128 * 40];
  __shared__ short phi_s[4][128 * 40];
  const int tid = threadIdx.x;
  const int bh = blockIdx.x >> 1, halfI = blockIdx.x & 1;
  for (int i = tid; i < 128 * 32; i += 256)
    proj_s[(i >> 5) * 40 + (i & 31)] = projb[i];
  __syncthreads();
  const int lane = tid & 63, wv = tid >> 6;
  const int quad = lane >> 4, l15 = lane & 15;
  const short* kb = kk + (size_t)bh * SDIM * DHEAD;
  const short* vb = vt + (size_t)bh * DHEAD * SDIM;
  short* myphi = phi_s[wv];
  const f32x4 vzero = {0.f, 0.f, 0.f, 0.f};
  f32x4 cacc[8][2];
  float ks_acc[8];
#pragma unroll
  for (int i = 0; i < 8; ++i) { cacc[i][0] = vzero; cacc[i][1] = vzero; ks_acc[i] = 0.f; }

  for (int ch = halfI * 4 + wv; ch < 98; ch += 8) {
    const int tok0 = ch * 32;
    short8 afr[2];
    afr[0] = *(const short8*)&kb[(size_t)(tok0 + l15) * DHEAD + quad * 8];
    afr[1] = *(const short8*)&kb[(size_t)(tok0 + 16 + l15) * DHEAD + quad * 8];
#pragma unroll
    for (int cf = 0; cf < 8; ++cf) {
      const short8 bfr = *(const short8*)&proj_s[(cf * 16 + l15) * 40 + quad * 8];
      const float epsv = (cf < 6) ? 1e-3f : ((cf == 6) ? ((l15 < 14) ? 1e-3f : 0.f) : 0.f);
#pragma unroll
      for (int fr = 0; fr < 2; ++fr) {
        f32x4 p = mfma16(afr[fr], bfr, vzero);
        unsigned short h4[4];
        float srow = 0.f;
#pragma unroll
        for (int r = 0; r < 4; ++r) {
          const float pv = fmaxf(p[r], 0.f) + epsv;
          srow += pv;
          h4[r] = f2bf(pv);
        }
        ks_acc[cf] += srow;
        *(unsigned long long*)&myphi[(cf * 16 + l15) * 40 + fr * 16 + quad * 4] = pack4(h4);
      }
    }
    short8 bv2[2];
    bv2[0] = *(const short8*)&vb[(size_t)l15 * SDIM + tok0 + quad * 8];
    bv2[1] = *(const short8*)&vb[(size_t)(16 + l15) * SDIM + tok0 + quad * 8];
#pragma unroll
    for (int mfr = 0; mfr < 8; ++mfr) {
      const short8 a2 = *(const short8*)&myphi[(mfr * 16 + l15) * 40 + quad * 8];
      cacc[mfr][0] = mfma16(a2, bv2[0], cacc[mfr][0]);
      cacc[mfr][1] = mfma16(a2, bv2[1], cacc[mfr][1]);
    }
  }
#pragma unroll
  for (int cf = 0; cf < 8; ++cf) {
    float v = ks_acc[cf];
    v += __shfl_xor(v, 16);
    v += __shfl_xor(v, 32);
    if (lane < 16) atomicAdd(&ksum[bh * 128 + cf * 16 + lane], v);
  }
  float* cb = ctx_acc + (size_t)bh * 4096;
#pragma unroll
  for (int mfr = 0; mfr < 8; ++mfr)
#pragma unroll
    for (int df = 0; df < 2; ++df)
#pragma unroll
      for (int r = 0; r < 4; ++r)
        atomicAdd(&cb[(mfr * 16 + quad * 4 + r) * 32 + df * 16 + l15], cacc[mfr][df][r]);
}

// ctx_T[bh][48][128] bf16: rows 0..31 = ctx^T (d-major), row 32 = ksum, 33..47 = 0
__global__ void ctx_finalize(const float* __restrict__ ctx_acc, const float* __restrict__ ksum,
                             short* __restrict__ ctx_T) {
  const int bh = blockIdx.x;
  const float* ca = ctx_acc + (size_t)bh * 4096;
  const float* ks = ksum + bh * 128;
  short* ct = ctx_T + (size_t)bh * 48 * 128;
  for (int i = threadIdx.x; i < 48 * 128; i += 256) {
    const int row = i >> 7, mf = i & 127;
    const float v = (row < 32) ? ca[mf * 32 + row] : ((row == 32) ? ks[mf] : 0.f);
    ct[i] = (short)f2bf(v);
  }
}

// Phase 2: phi_q via MFMA, out = phi_q@ctx * 1/denom; writes Y NHWC bf16
// via per-wave LDS transpose.
__global__ __launch_bounds__(256, 2)
void attn_phase2(const short* __restrict__ qq, const short* __restrict__ ctx_T,
                 const short* __restrict__ projb, short* __restrict__ Yn) {
  __shared__ short proj_s[128 * 40];
  __shared__ short ctx_s[48 * 136];
  __shared__ short phi_s[4][32 * 136];
  const int tid = threadIdx.x;
  const int bh = blockIdx.x >> 1, halfI = blockIdx.x & 1;
  for (int i = tid; i < 128 * 32; i += 256)
    proj_s[(i >> 5) * 40 + (i & 31)] = projb[i];
  {
    const short* ct = ctx_T + (size_t)bh * 48 * 128;
    for (int i = tid; i < 48 * 128; i += 256)
      ctx_s[(i >> 7) * 136 + (i & 127)] = ct[i];
  }
  __syncthreads();
  const int lane = tid & 63, wv = tid >> 6;
  const int quad = lane >> 4, l15 = lane & 15;
  const int b = bh >> 3, head = bh & 7;
  const short* qb = qq + (size_t)bh * SDIM * DHEAD;
  short* myphi = phi_s[wv];
  const f32x4 vzero = {0.f, 0.f, 0.f, 0.f};

  for (int ch = halfI * 4 + wv; ch < 98; ch += 8) {
    const int tok0 = ch * 32;
    short8 afr[2];
    afr[0] = *(const short8*)&qb[(size_t)(tok0 + l15) * DHEAD + quad * 8];
    afr[1] = *(const short8*)&qb[(size_t)(tok0 + 16 + l15) * DHEAD + quad * 8];
#pragma unroll
    for (int cf = 0; cf < 8; ++cf) {
      const short8 bfr = *(const short8*)&proj_s[(cf * 16 + l15) * 40 + quad * 8];
      const float epsv = (cf < 6) ? 1e-3f : ((cf == 6) ? ((l15 < 14) ? 1e-3f : 0.f) : 0.f);
#pragma unroll
      for (int fr = 0; fr < 2; ++fr) {
        f32x4 p = mfma16(afr[fr], bfr, vzero);
#pragma unroll
        for (int r = 0; r < 4; ++r) {
          const float pv = fmaxf(p[r], 0.f) + epsv;
          myphi[(fr * 16 + quad * 4 + r) * 136 + cf * 16 + l15] = (short)f2bf(pv);
        }
      }
    }
    f32x4 oacc[2][3];
#pragma unroll
    for (int fr = 0; fr < 2; ++fr)
#pragma unroll
      for (int c3 = 0; c3 < 3; ++c3) oacc[fr][c3] = vzero;
#pragma unroll
    for (int ksI = 0; ksI < 4; ++ksI) {
      short8 a3[2];
      a3[0] = *(const short8*)&myphi[l15 * 136 + ksI * 32 + quad * 8];
      a3[1] = *(const short8*)&myphi[(16 + l15) * 136 + ksI * 32 + quad * 8];
#pragma unroll
      for (int c3 = 0; c3 < 3; ++c3) {
        const short8 b3 = *(const short8*)&ctx_s[(c3 * 16 + l15) * 136 + ksI * 32 + quad * 8];
        oacc[0][c3] = mfma16(a3[0], b3, oacc[0][c3]);
        oacc[1][c3] = mfma16(a3[1], b3, oacc[1][c3]);
      }
    }
#pragma unroll
    for (int fr = 0; fr < 2; ++fr) {
      float dinv[4];
#pragma unroll
      for (int r = 0; r < 4; ++r) {
        const float den = __shfl(oacc[fr][2][r], quad << 4);
        dinv[r] = 1.f / den;
      }
#pragma unroll
      for (int c3 = 0; c3 < 2; ++c3)
#pragma unroll
        for (int r = 0; r < 4; ++r)
          myphi[(fr * 16 + quad * 4 + r) * 40 + c3 * 16 + l15] =
              (short)f2bf(oacc[fr][c3][r] * dinv[r]);
    }
    const size_t trow0 = (size_t)(b * SDIM + tok0) * 256 + head * 32;
#pragma unroll
    for (int it = 0; it < 2; ++it) {
      const int idx = it * 64 + lane;
      const int tl = idx >> 2, c4 = idx & 3;
      const short8 vv = *(const short8*)&myphi[tl * 40 + c4 * 8];
      *(short8*)&Yn[trow0 + (size_t)tl * 256 + c4 * 8] = vv;
    }
  }
}

// ---------------------------------------------------------------------------
// Wo GEMM: M=64, N=256 (grid 784). A = Y NHWC bf16, B = WoT packed.
// z = Y@Wo + bo + xh (NHWC bf16) via LDS transpose epilogue.
__global__ __launch_bounds__(256, 4)
void wo_gemm(const short* __restrict__ Yn, const short* __restrict__ WoT,
             const float* __restrict__ bo, const short* __restrict__ xh,
             short* __restrict__ z) {
  __shared__ short A_s[64 * 264];  // staging uses pitch 256; epilogue zt pitch 264
  const int tid = threadIdx.x;
  const int mtile = blockIdx.x;
  const int token0 = mtile * 64;
  {
    const int trow = tid >> 5, cch = tid & 31;
    const short* src = Yn + (size_t)token0 * 256;
#pragma unroll
    for (int i = 0; i < 8; ++i) {
      const int tok = trow + i * 8;
      const short8 vv = *(const short8*)&src[tok * 256 + cch * 8];
      const int phys = cch ^ (tok & 31);
      *(short8*)&A_s[tok * 256 + phys * 8] = vv;
    }
  }
  __syncthreads();

  const int lane = tid & 63, wv = tid >> 6;
  const int quad = lane >> 4, l15 = lane & 15;
  const f32x4 vzero = {0.f, 0.f, 0.f, 0.f};
  f32x4 acc[4][4];
#pragma unroll
  for (int i = 0; i < 4; ++i)
#pragma unroll
    for (int j = 0; j < 4; ++j) acc[i][j] = vzero;
#pragma unroll
  for (int ks = 0; ks < 8; ++ks) {
    short8 af[4], bfr[4];
#pragma unroll
    for (int rf = 0; rf < 4; ++rf) {
      const int row = rf * 16 + l15;
      const int phys = (ks * 4 + quad) ^ (row & 31);
      af[rf] = *(const short8*)&A_s[row * 256 + phys * 8];
    }
#pragma unroll
    for (int cf = 0; cf < 4; ++cf)
      bfr[cf] = *(const short8*)&WoT[((((ks << 4) | (wv << 2) | cf) << 6) | lane) << 3];
#pragma unroll
    for (int rf = 0; rf < 4; ++rf)
#pragma unroll
      for (int cf = 0; cf < 4; ++cf)
        acc[rf][cf] = mfma16(af[rf], bfr[cf], acc[rf][cf]);
  }
  // epilogue: C-frag -> LDS [tok][oc] (bias fused), then coalesced NHWC rows (+xh)
  __syncthreads();
  short* zt = A_s;
#pragma unroll
  for (int cf = 0; cf < 4; ++cf) {
    const int ocl = wv * 64 + cf * 16 + l15;
    const float bias = bo[ocl];
#pragma unroll
    for (int rf = 0; rf < 4; ++rf) {
      const int tl = rf * 16 + quad * 4;
#pragma unroll
      for (int r = 0; r < 4; ++r)
        zt[(tl + r) * 264 + ocl] = (short)f2bf(acc[rf][cf][r] + bias);
    }
  }
  __syncthreads();
#pragma unroll
  for (int j = 0; j < 8; ++j) {
    const int idx = tid + j * 256;  // 0..2047
    const int tl = idx >> 5, ch = idx & 31;
    const short8 zv = *(const short8*)&zt[tl * 264 + ch * 8];
    const size_t gbase = (size_t)(token0 + tl) * 256 + ch * 8;
    const short8 xv = *(const short8*)&xh[gbase];
    unsigned short h[8];
#pragma unroll
    for (int jj = 0; jj < 8; ++jj) h[jj] = f2bf(bf2f(zv[jj]) + bf2f(xv[jj]));
    unsigned long long* p = (unsigned long long*)&z[gbase];
    p[0] = pack4(h);
    p[1] = pack4(h + 4);
  }
}

// ---------------------------------------------------------------------------
// Conv 3x3 implicit GEMM: M=64, N=256 (grid 784). A = u2 NHWC bf16 patches,
// B = Bconv packed. Register-prefetch of next-off staging overlaps compute.
__global__ __launch_bounds__(256, 3)
void conv_gemm(const short* __restrict__ u2, const short* __restrict__ Bc,
               const float* __restrict__ x, float* __restrict__ out) {
  __shared__ short A_s[64 * 256];
  const int tid = threadIdx.x;
  const int mtile = blockIdx.x;
  const int bb = mtile / 49, s0 = (mtile - bb * 49) * 64;
  const short* ub = u2 + (size_t)bb * SDIM * 256;
  const int trow = tid >> 5, cch = tid & 31;
  const int lane = tid & 63, wv = tid >> 6;
  const int quad = lane >> 4, l15 = lane & 15;
  const f32x4 vzero = {0.f, 0.f, 0.f, 0.f};
  f32x4 acc[4][4];
#pragma unroll
  for (int i = 0; i < 4; ++i)
#pragma unroll
    for (int j = 0; j < 4; ++j) acc[i][j] = vzero;

  short8 pref[8];
#define LOAD_OFF(OFF)                                                          \
  {                                                                            \
    const int dy = (OFF) / 3 - 1, dx = (OFF) - ((OFF) / 3) * 3 - 1;            \
    _Pragma("unroll") for (int i = 0; i < 8; ++i) {                            \
      const int tok = trow + i * 8;                                            \
      const int s = s0 + tok;                                                  \
      const int yy = s / 56, xx = s - yy * 56;                                 \
      const int ny = yy + dy, nx = xx + dx;                                    \
      short8 vv = {0, 0, 0, 0, 0, 0, 0, 0};                                    \
      if (((unsigned)ny < 56u) && ((unsigned)nx < 56u))                        \
        vv = *(const short8*)&ub[(size_t)(ny * 56 + nx) * 256 + cch * 8];      \
      pref[i] = vv;                                                            \
    }                                                                          \
  }

  LOAD_OFF(0);
  for (int off = 0; off < 9; ++off) {
    if (off) __syncthreads();
#pragma unroll
    for (int i = 0; i < 8; ++i) {
      const int tok = trow + i * 8;
      const int phys = cch ^ (tok & 31);
      *(short8*)&A_s[tok * 256 + phys * 8] = pref[i];
    }
    __syncthreads();
    if (off < 8) LOAD_OFF(off + 1);  // overlap next staging loads with compute
    const short* Bp = Bc + (off << 16);
#pragma unroll
    for (int ks = 0; ks < 8; ++ks) {
      short8 af[4], bfr[4];
#pragma unroll
      for (int rf = 0; rf < 4; ++rf) {
        const int row = rf * 16 + l15;
        const int phys = (ks * 4 + quad) ^ (row & 31);
        af[rf] = *(const short8*)&A_s[row * 256 + phys * 8];
      }
#pragma unroll
      for (int cf = 0; cf < 4; ++cf)
        bfr[cf] = *(const short8*)&Bp[((((ks << 4) | (wv << 2) | cf) << 6) | lane) << 3];
#pragma unroll
      for (int rf = 0; rf < 4; ++rf)
#pragma unroll
        for (int cf = 0; cf < 4; ++cf)
          acc[rf][cf] = mfma16(af[rf], bfr[cf], acc[rf][cf]);
    }
  }
#undef LOAD_OFF
#pragma unroll
  for (int cf = 0; cf < 4; ++cf) {
    const int oc = wv * 64 + cf * 16 + l15;
#pragma unroll
    for (int rf = 0; rf < 4; ++rf) {
      const int ss = s0 + rf * 16 + quad * 4;
      const size_t base = ((size_t)(bb * CDIM + oc)) * SDIM + ss;
      const f32x4 xv = *(const f32x4*)(x + base);
      f32x4 res;
#pragma unroll
      for (int r = 0; r < 4; ++r) res[r] = acc[rf][cf][r] + xv[r];
      *(f32x4*)(out + base) = res;
    }
  }
}

// ---------------------------------------------------------------------------
extern "C" void kernel_launch(void* const* d_in, const int* in_sizes, int n_in,
                              void* d_out, int out_size, void* d_ws, size_t ws_size,
                              hipStream_t stream) {
  const float* x      = (const float*)d_in[0];
  const float* bn1_g  = (const float*)d_in[1];
  const float* bn1_b  = (const float*)d_in[2];
  const float* bn2_g  = (const float*)d_in[3];
  const float* bn2_b  = (const float*)d_in[4];
  const float* Wq     = (const float*)d_in[5];
  const float* bq     = (const float*)d_in[6];
  const float* Wk     = (const float*)d_in[7];
  const float* bk     = (const float*)d_in[8];
  const float* Wv     = (const float*)d_in[9];
  const float* bv     = (const float*)d_in[10];
  const float* Wo     = (const float*)d_in[11];
  const float* bo     = (const float*)d_in[12];
  const float* proj   = (const float*)d_in[13];
  const float* conv_w = (const float*)d_in[14];
  float* out = (float*)d_out;
  char* ws = (char*)d_ws;

  // ---- workspace layout (54.2 MB) ----
  const size_t OFF_K     = 0;           // bf16 k; then Y NHWC; then u2
  const size_t OFF_V     = 25690112;    // bf16 vT; then z NHWC
  const size_t OFF_BQKV  = 51380224;    // 393,216 B (packed)
  const size_t OFF_WOT   = 51773440;    // 131,072 B (packed)
  const size_t OFF_BCONV = 51904512;    // 1,179,648 B (packed)
  const size_t OFF_PROJB = 53084160;    // 8,192 B
  const size_t OFF_CTXA  = 53092352;    // 2,097,152 B
  const size_t OFF_KSUM  = 55189504;    // 65,536 B
  const size_t OFF_BN1S  = 55255040;    // 2,048 B
  const size_t OFF_BN2S  = 55257088;    // 2,048 B
  const size_t OFF_SC1   = 55259136;    // 2,048 B
  const size_t OFF_SC2   = 55261184;    // 2,048 B
  const size_t OFF_CTXT  = 55263232;    // 1,572,864 B
  const size_t WS_NEEDED = 56836096;

  if (ws_size < WS_NEEDED) {
    zero_kernel<<<2048, 256, 0, stream>>>(out, out_size);
    return;
  }

  // d_out doubles as scratch: [q (25.7MB) | u1 then xh (25.7MB)]
  short* qb    = (short*)d_out;
  short* half2 = (short*)d_out + 12845056;
  short* kb    = (short*)(ws + OFF_K);
  short* vtb   = (short*)(ws + OFF_V);
  short* Yn    = (short*)(ws + OFF_K);
  short* zbuf  = (short*)(ws + OFF_V);
  short* u2b   = (short*)(ws + OFF_K);
  short* Bqkv  = (short*)(ws + OFF_BQKV);
  short* WoT   = (short*)(ws + OFF_WOT);
  short* Bconv = (short*)(ws + OFF_BCONV);
  short* projb = (short*)(ws + OFF_PROJB);
  float* ctxa  = (float*)(ws + OFF_CTXA);
  float* ksum  = (float*)(ws + OFF_KSUM);
  float* bn1s  = (float*)(ws + OFF_BN1S);
  float* bn2s  = (float*)(ws + OFF_BN2S);
  float* sc1   = (float*)(ws + OFF_SC1);
  float* sc2   = (float*)(ws + OFF_SC2);
  short* ctxT  = (short*)(ws + OFF_CTXT);

  zero_kernel<<<512, 256, 0, stream>>>(ctxa, (2097152 + 65536 + 2048 + 2048) / 4);
  prep_kernel<<<256, 256, 0, stream>>>(Wq, Wk, Wv, Wo, proj, conv_w, Bqkv, WoT, Bconv, projb);
  bn_stats_kernel<<<4096, 256, 0, stream>>>(x, bn1s);
  bn_final_kernel<<<1, 256, 0, stream>>>(bn1s, bn1_g, bn1_b, sc1);
  transpose_x<<<dim3(784, 4), 256, 0, stream>>>(x, sc1, half2, 1);
  qkv_gemm<<<dim3(784, 3), 256, 0, stream>>>(half2, Bqkv, bq, bk, bv, qb, kb, vtb);
  attn_phase1<<<256, 256, 0, stream>>>(kb, vtb, projb, ctxa, ksum);
  ctx_finalize<<<128, 256, 0, stream>>>(ctxa, ksum, ctxT);
  attn_phase2<<<256, 256, 0, stream>>>(qb, ctxT, projb, Yn);
  transpose_x<<<dim3(784, 4), 256, 0, stream>>>(x, sc1, half2, 0);
  wo_gemm<<<784, 256, 0, stream>>>(Yn, WoT, bo, half2, zbuf);
  bn_stats_nhwc<<<784, 256, 0, stream>>>(zbuf, bn2s);
  bn_final_kernel<<<1, 256, 0, stream>>>(bn2s, bn2_g, bn2_b, sc2);
  u2_kernel<<<1024, 256, 0, stream>>>(zbuf, sc2, u2b);
  conv_gemm<<<784, 256, 0, stream>>>(u2b, Bconv, x, out);
}